// Round 14
// baseline (398.346 us; speedup 1.0000x reference)
//
#include <hip/hip_runtime.h>
#include <hip/hip_bf16.h>

typedef unsigned short u16;
typedef unsigned int u32;
typedef __attribute__((ext_vector_type(4))) float f32x4;
typedef __attribute__((ext_vector_type(16))) float f32x16;
typedef __attribute__((ext_vector_type(8))) __bf16 bf16x8;
typedef __attribute__((ext_vector_type(4))) u16 u16x4;
typedef __attribute__((ext_vector_type(8))) u16 u16x8;
typedef __attribute__((ext_vector_type(4))) u32 u32x4;

#define START_POS 3072
#define NKV 4096
#define HD_ 128
#define SEQ 1024
#define DIN_ 4096
#define DQKV 6144

__device__ __forceinline__ void gll16(const void* g, void* l) {
  __builtin_amdgcn_global_load_lds((const __attribute__((address_space(1))) u32*)g,
                                   (__attribute__((address_space(3))) u32*)l, 16, 0, 0);
}
__device__ __forceinline__ u16 f2bf(float f) {
  u32 u = __builtin_bit_cast(u32, f);
  return (u16)((u + 0x7fffu + ((u >> 16) & 1u)) >> 16);
}
__device__ __forceinline__ u32 pack2bf(float a, float b) {
  __hip_bfloat162 t = __float22bfloat162_rn(float2{a, b});  // low=a, high=b, RNE
  u32 u; __builtin_memcpy(&u, &t, 4);
  return u;
}
__device__ __forceinline__ f32x4 mfma16(bf16x8 a, bf16x8 b, f32x4 c) {
  return __builtin_amdgcn_mfma_f32_16x16x32_bf16(a, b, c, 0, 0, 0);
}
__device__ __forceinline__ f32x16 mfma32(bf16x8 a, bf16x8 b, f32x16 c) {
  return __builtin_amdgcn_mfma_f32_32x32x16_bf16(a, b, c, 0, 0, 0);
}

// ---- transpose+convert W f32 [K=4096][N] -> Wt bf16 [N][4096] ----
__global__ __launch_bounds__(256) void wtrans(const float* __restrict__ W,
    u16* __restrict__ Wt, int N, int ntn, int row_off)
{
  __shared__ float T[64][68];
  int bid = blockIdx.x;
  int nt = bid % ntn, kt = bid / ntn;
  int t = threadIdx.x;
  int kl = t >> 4, nl4 = (t & 15) << 2;
#pragma unroll
  for (int r = 0; r < 4; r++) {
    int row = r * 16 + kl;
    f32x4 v = *(const f32x4*)(W + (size_t)(kt * 64 + row) * N + nt * 64 + nl4);
    T[row][nl4] = v[0]; T[row][nl4 + 1] = v[1]; T[row][nl4 + 2] = v[2]; T[row][nl4 + 3] = v[3];
  }
  __syncthreads();
  int nl = t >> 2, k0 = (t & 3) << 4;
  u16x8 lo, hi;
#pragma unroll
  for (int j = 0; j < 8; j++) lo[j] = f2bf(T[k0 + j][nl]);
#pragma unroll
  for (int j = 0; j < 8; j++) hi[j] = f2bf(T[k0 + 8 + j][nl]);
  u16* dst = Wt + (size_t)(row_off + nt * 64 + nl) * 4096 + kt * 64 + k0;
  *(u16x8*)dst = lo;
  *(u16x8*)(dst + 8) = hi;
}

// ---- f32 -> bf16 convert ----
__global__ __launch_bounds__(256) void cvt_bf16(const float* __restrict__ src,
    u16* __restrict__ dst, int n4)
{
  int i = blockIdx.x * 256 + threadIdx.x;
  if (i >= n4) return;
  f32x4 v = *(const f32x4*)(src + (size_t)i * 4);
  u16x4 o;
#pragma unroll
  for (int j = 0; j < 4; j++) o[j] = f2bf(v[j]);
  *(u16x4*)(dst + (size_t)i * 4) = o;
}

// ---- bf16 GEMM v2: 128x64 tile, BK=32, double-buffered LDS, 2-phase prefetch ----
__global__ __launch_bounds__(256) void gemm_bt(
    const u16* __restrict__ A, const u16* __restrict__ Bt,
    float* __restrict__ C, int N, int K, int nbx)
{
  __shared__ u16 As[2 * 128 * 32];
  __shared__ u16 Bs[2 * 64 * 32];
  int nwg = (int)gridDim.x;
  int orig = blockIdx.x;
  int q8 = nwg >> 3, r8 = nwg & 7;
  int xcd = orig & 7, jj = orig >> 3;
  int wgid = (xcd < r8 ? xcd * (q8 + 1) : r8 * (q8 + 1) + (xcd - r8) * q8) + jj;
  int by = wgid / nbx, bx = wgid % nbx;
  int tid = threadIdx.x, lane = tid & 63, wid = tid >> 6;
  int wr = wid >> 1, wc = wid & 1;
  int c = lane & 15, hh = lane >> 4;
  int lrow = wid * 16 + (lane >> 2);       // 0..63
  int ksl = (lane & 3) << 3;
  const u16* aS0 = A + (size_t)(by * 128 + lrow) * K + ksl;
  const u16* bS0 = Bt + (size_t)(bx * 64 + lrow) * K + ksl;

#define GSTAGE(buf, kk) do { \
  gll16(aS0 + (kk), As + (buf) * 4096 + wid * 512); \
  gll16(aS0 + (size_t)64 * K + (kk), As + (buf) * 4096 + 2048 + wid * 512); \
  gll16(bS0 + (kk), Bs + (buf) * 2048 + wid * 512); \
} while (0)

  f32x4 acc[4][2] = {};
  int nk = K >> 5;
  int cur = 0;
  GSTAGE(0, 0);
  __syncthreads();                          // tile 0 resident
  for (int kt = 0; kt < nk; kt++) {
    if (kt + 1 < nk) GSTAGE(cur ^ 1, (kt + 1) * 32);  // prefetch next (hides under compute)
    const u16* Ab = As + cur * 4096;
    const u16* Bb = Bs + cur * 2048;
    bf16x8 af[4], bf[2];
#pragma unroll
    for (int i = 0; i < 4; i++)
      af[i] = *(const bf16x8*)(Ab + (wr * 64 + i * 16 + c) * 32 + hh * 8);
#pragma unroll
    for (int i = 0; i < 2; i++)
      bf[i] = *(const bf16x8*)(Bb + (wc * 32 + i * 16 + c) * 32 + hh * 8);
    __builtin_amdgcn_s_setprio(1);
#pragma unroll
    for (int mi = 0; mi < 4; mi++)
#pragma unroll
      for (int ni = 0; ni < 2; ni++)
        acc[mi][ni] = mfma16(af[mi], bf[ni], acc[mi][ni]);
    __builtin_amdgcn_s_setprio(0);
    __syncthreads();                        // prefetch landed + all waves done with cur
    cur ^= 1;
  }
#undef GSTAGE
  int row0 = by * 128 + wr * 64 + hh * 4;
  int col0 = bx * 64 + wc * 32 + c;
#pragma unroll
  for (int mi = 0; mi < 4; mi++)
#pragma unroll
    for (int ni = 0; ni < 2; ni++)
#pragma unroll
      for (int i = 0; i < 4; i++)
        C[(size_t)(row0 + mi * 16 + i) * N + col0 + ni * 16] = acc[mi][ni][i];
}

// ---- RoPE on q part of qkv -> qb bf16 [32][1024][128], PRE-SCALED by log2(e)/sqrt(128) ----
__global__ __launch_bounds__(256) void rope_q(const float* __restrict__ qkv,
    const float* __restrict__ cosb, const float* __restrict__ sinb, u16* __restrict__ qb)
{
  const float C2 = 0.12751744f;
  int tid = blockIdx.x * 256 + threadIdx.x;  // 524288
  int dq = tid & 15, h = (tid >> 4) & 31, s = tid >> 9;
  int d = dq << 2;
  const float* base = qkv + (size_t)s * DQKV + h * HD_ + d;
  f32x4 a = *(const f32x4*)base;
  f32x4 b2 = *(const f32x4*)(base + 64);
  f32x4 cc = *(const f32x4*)(cosb + (size_t)(START_POS + s) * HD_ + d);
  f32x4 sn = *(const f32x4*)(sinb + (size_t)(START_POS + s) * HD_ + d);
  u16x4 o1, o2;
#pragma unroll
  for (int i = 0; i < 4; i++) {
    o1[i] = f2bf((a[i] * cc[i] - b2[i] * sn[i]) * C2);
    o2[i] = f2bf((b2[i] * cc[i] + a[i] * sn[i]) * C2);
  }
  u16* dst = qb + ((size_t)h * SEQ + s) * HD_ + d;
  *(u16x4*)dst = o1;
  *(u16x4*)(dst + 64) = o2;
}

// ---- RoPE on k part -> keys f32 output (pos>=3072) + kb bf16 ----
__global__ __launch_bounds__(256) void rope_k(const float* __restrict__ qkv,
    const float* __restrict__ cosb, const float* __restrict__ sinb,
    float* __restrict__ keys, u16* __restrict__ kbb)
{
  int tid = blockIdx.x * 256 + threadIdx.x;  // 131072
  int dq = tid & 15, g = (tid >> 4) & 7, s = tid >> 7;
  int d = dq << 2;
  const float* base = qkv + (size_t)s * DQKV + DIN_ + g * HD_ + d;
  f32x4 a = *(const f32x4*)base;
  f32x4 b2 = *(const f32x4*)(base + 64);
  f32x4 cc = *(const f32x4*)(cosb + (size_t)(START_POS + s) * HD_ + d);
  f32x4 sn = *(const f32x4*)(sinb + (size_t)(START_POS + s) * HD_ + d);
  f32x4 o1, o2;
  u16x4 p1, p2;
#pragma unroll
  for (int i = 0; i < 4; i++) {
    o1[i] = a[i] * cc[i] - b2[i] * sn[i];
    o2[i] = b2[i] * cc[i] + a[i] * sn[i];
    p1[i] = f2bf(o1[i]);
    p2[i] = f2bf(o2[i]);
  }
  size_t off = ((size_t)g * NKV + START_POS + s) * HD_ + d;
  *(f32x4*)(keys + off) = o1;
  *(f32x4*)(keys + off + 64) = o2;
  *(u16x4*)(kbb + off) = p1;
  *(u16x4*)(kbb + off + 64) = p2;
}

// ---- copy v part -> values f32 output (pos>=3072) ----
__global__ __launch_bounds__(256) void copy_vnew(const float* __restrict__ qkv,
    float* __restrict__ values)
{
  int tid = blockIdx.x * 256 + threadIdx.x;  // 262144
  int dq = tid & 31, g = (tid >> 5) & 7, s = tid >> 8;
  int d = dq << 2;
  f32x4 v = *(const f32x4*)(qkv + (size_t)s * DQKV + DIN_ + 1024 + g * HD_ + d);
  *(f32x4*)(values + ((size_t)g * NKV + START_POS + s) * HD_ + d) = v;
}

// ---- copy prev_k/prev_v -> keys/values f32 outputs + kb bf16 ----
__global__ __launch_bounds__(256) void prev_copy(const float* __restrict__ pk,
    const float* __restrict__ pv, float* __restrict__ keys, float* __restrict__ values,
    u16* __restrict__ kbb)
{
  int idx = blockIdx.x * 256 + threadIdx.x;  // 786432 quads
  int d4 = idx & 31;
  int rest = idx >> 5;
  int p = rest % 3072, g = rest / 3072;
  f32x4 kq = *(const f32x4*)(pk + (size_t)idx * 4);
  f32x4 vq = *(const f32x4*)(pv + (size_t)idx * 4);
  size_t off = ((size_t)g * NKV + p) * HD_ + d4 * 4;
  *(f32x4*)(keys + off) = kq;
  *(f32x4*)(values + off) = vq;
  u16x4 kb4;
#pragma unroll
  for (int i = 0; i < 4; i++) kb4[i] = f2bf(kq[i]);
  *(u16x4*)(kbb + off) = kb4;
}

// ---- build vT bf16 [8][128][4096] from prev_v (pos<3072) / qkv v-cols ----
__global__ __launch_bounds__(256) void vtrans(const float* __restrict__ pv,
    const float* __restrict__ qkv, u16* __restrict__ vT)
{
  __shared__ float T[64][68];
  int bid = blockIdx.x;  // 1024 = g(8) * pt(64) * dt(2)
  int dt = bid & 1, pt = (bid >> 1) & 63, g = bid >> 7;
  int t = threadIdx.x;
  int pl = t >> 4, dl4 = (t & 15) << 2;
#pragma unroll
  for (int r = 0; r < 4; r++) {
    int row = r * 16 + pl;
    int pos = pt * 64 + row;
    f32x4 v;
    if (pos < START_POS)
      v = *(const f32x4*)(pv + ((size_t)g * START_POS + pos) * HD_ + dt * 64 + dl4);
    else
      v = *(const f32x4*)(qkv + (size_t)(pos - START_POS) * DQKV + 5120 + g * HD_ + dt * 64 + dl4);
    T[row][dl4] = v[0]; T[row][dl4 + 1] = v[1]; T[row][dl4 + 2] = v[2]; T[row][dl4 + 3] = v[3];
  }
  __syncthreads();
  int dl = t >> 2, p0 = (t & 3) << 4;
  u16x8 lo, hi;
#pragma unroll
  for (int j = 0; j < 8; j++) lo[j] = f2bf(T[p0 + j][dl]);
#pragma unroll
  for (int j = 0; j < 8; j++) hi[j] = f2bf(T[p0 + 8 + j][dl]);
  u16* dst = vT + ((size_t)g * HD_ + dt * 64 + dl) * NKV + pt * 64 + p0;
  *(u16x8*)dst = lo;
  *(u16x8*)(dst + 8) = hi;
}

// ---- flash attention v7: 3-way KV split (1536 blocks = 6/CU, 3 waves/SIMD),
// ---- 24KB LDS (K dbuf + V single buf), counted vmcnt + raw barriers (no drains).
// ---- Q pre-scaled by C2 (exp2-domain softmax). Verified v5d compute core. ----
__global__ __launch_bounds__(128, 2) void attn_fwd(
    const u16* __restrict__ qb, const u16* __restrict__ kb,
    const u16* __restrict__ vT, float* __restrict__ Opart, float* __restrict__ Ml)
{
  __shared__ u16 Ks[2 * 32 * 128];   // dbuf K, 16B-slot XOR swizzle (16KB)
  __shared__ u16 Vs[128 * 32];       // single-buf V, slot^((d>>1)&3) swizzle (8KB)
  int bid = blockIdx.x;
  int g = bid & 7, j = bid >> 3;     // j in [0,192)
  int sp = j >> 6, jj = j & 63;      // sp in {0,1,2}
  int h = g * 4 + (jj >> 4), qt = jj & 15;
  int tid = threadIdx.x, lane = tid & 63, w = tid >> 6;
  int c32 = lane & 31, h8 = lane >> 5;
  int qw0 = qt * 64 + w * 32;
  bf16x8 Qf[8];
#pragma unroll
  for (int dc = 0; dc < 8; dc++)
    Qf[dc] = *(const bf16x8*)(qb + ((size_t)(h * 1024 + qw0 + c32)) * 128 + dc * 16 + h8 * 8);
  f32x16 O0 = {}, O1 = {}, O2 = {}, O3 = {};
  float Mx = -1e30f, Ls = 0.f;
  // 3-way balanced split of T = 98 + 2*qt tiles
  int T = 98 + 2 * qt;
  int t0 = (sp * T) / 3;
  int t1 = ((sp + 1) * T) / 3;

#define STAGE_K(tt, bo) do { \
  _Pragma("unroll") \
  for (int r = 0; r < 2; r++) { \
    int s = w * 256 + r * 128 + (lane & 63) + (lane >> 6) * 0; \
    int s2 = w * 256 + r * 128 + lane; \
    (void)s; \
    int krow = s2 >> 4, sl = s2 & 15; \
    gll16(kb + ((size_t)(g * 4096 + (tt) * 32 + krow)) * 128 + (sl ^ (krow & 7)) * 8, \
          Ks + (bo) + (w * 256 + r * 128) * 8); \
    int s3 = w * 256 + r * 128 + 64 + lane; \
    int krow2 = s3 >> 4, sl2_ = s3 & 15; \
    gll16(kb + ((size_t)(g * 4096 + (tt) * 32 + krow2)) * 128 + (sl2_ ^ (krow2 & 7)) * 8, \
          Ks + (bo) + (w * 256 + r * 128 + 64) * 8); \
  } \
} while (0)

#define STAGE_V(tt) do { \
  _Pragma("unroll") \
  for (int r = 0; r < 4; r++) { \
    int s = w * 256 + r * 64 + lane; \
    int d = s >> 2, sl2 = s & 3; \
    gll16(vT + ((size_t)(g * 128 + d)) * 4096 + (tt) * 32 + (sl2 ^ ((d >> 1) & 3)) * 8, \
          Vs + (w * 256 + r * 64) * 8); \
  } \
} while (0)

  int cur = 0;
  STAGE_K(t0, 0);                    // 4 gll16 (this wave)
  int vxr = (c32 >> 1) & 3;
  for (int t = t0; t < t1; t++) {
    bool last = (t + 1 >= t1);
    STAGE_V(t);                      // 4 gll16
    if (!last) STAGE_K(t + 1, (cur ^ 1) * 4096);  // 4 gll16
    // K(t) (own 4, issued last iter / prologue) retired; V(t)+K(t+1) still in flight
    if (!last) { asm volatile("s_waitcnt vmcnt(8)" ::: "memory"); }
    else       { asm volatile("s_waitcnt vmcnt(4)" ::: "memory"); }
    __builtin_amdgcn_sched_barrier(0);
    __builtin_amdgcn_s_barrier();    // all waves' K(t) visible
    __builtin_amdgcn_sched_barrier(0);
    const u16* Kb = Ks + cur * 4096;
    // S^T = K Q^T : two independent accumulator chains
    f32x16 S0 = {}, Sb = {};
    __builtin_amdgcn_s_setprio(1);
#pragma unroll
    for (int dc = 0; dc < 8; dc += 2) {
      int sxA = (2 * dc + h8) ^ (c32 & 7);
      int sxB = (2 * dc + 2 + h8) ^ (c32 & 7);
      bf16x8 kA = *(const bf16x8*)(Kb + (size_t)c32 * 128 + sxA * 8);
      bf16x8 kB = *(const bf16x8*)(Kb + (size_t)c32 * 128 + sxB * 8);
      S0 = mfma32(kA, Qf[dc], S0);
      Sb = mfma32(kB, Qf[dc + 1], Sb);
    }
    __builtin_amdgcn_s_setprio(0);
#pragma unroll
    for (int r = 0; r < 16; r++) S0[r] += Sb[r];
    // causal mask (near-diagonal tiles only; S in exp2-domain units)
    if (t * 32 + 31 > START_POS + qw0) {
      int qa = START_POS + qw0 + c32;
#pragma unroll
      for (int r = 0; r < 16; r++) {
        int kvo = t * 32 + (r & 3) + 8 * (r >> 2) + 4 * h8;
        if (kvo > qa) S0[r] = -1e30f;
      }
    }
    // row max: 15-op tree + cross-half via shfl_xor(32)
    float tm[16];
#pragma unroll
    for (int r = 0; r < 16; r++) tm[r] = S0[r];
#pragma unroll
    for (int sft = 8; sft >= 1; sft >>= 1)
#pragma unroll
      for (int r = 0; r < sft; r++) tm[r] = fmaxf(tm[r], tm[r + sft]);
    float full = fmaxf(tm[0], __shfl_xor(tm[0], 32));
    // defer-max (T13), exp2-domain threshold 8
    if (!__all(full <= Mx + 8.0f)) {
      float Mn = fmaxf(Mx, full);
      float al = exp2f(Mx - Mn);
      Mx = Mn;
      Ls *= al;
#pragma unroll
      for (int r = 0; r < 16; r++) { O0[r] *= al; O1[r] *= al; O2[r] *= al; O3[r] *= al; }
    }
#pragma unroll
    for (int r = 0; r < 16; r++) S0[r] = exp2f(S0[r] - Mx);
    // row sum
    float ts[16];
#pragma unroll
    for (int r = 0; r < 16; r++) ts[r] = S0[r];
#pragma unroll
    for (int sft = 8; sft >= 1; sft >>= 1)
#pragma unroll
      for (int r = 0; r < sft; r++) ts[r] = ts[r] + ts[r + sft];
    Ls += ts[0] + __shfl_xor(ts[0], 32);
    // pack P + cross-half exchange (verified routing)
    u32 pk0[8], x0[8];
#pragma unroll
    for (int m = 0; m < 8; m++) pk0[m] = pack2bf(S0[2 * m], S0[2 * m + 1]);
#pragma unroll
    for (int m = 0; m < 8; m++) x0[m] = __shfl_xor(pk0[m], 32);
    bf16x8 pbf[2];
    {
      u32x4 f0 = { h8 ? x0[2] : pk0[0], h8 ? x0[3] : pk0[1],
                   h8 ? pk0[2] : x0[0], h8 ? pk0[3] : x0[1] };
      u32x4 f1 = { h8 ? x0[6] : pk0[4], h8 ? x0[7] : pk0[5],
                   h8 ? pk0[6] : x0[4], h8 ? pk0[7] : x0[5] };
      pbf[0] = __builtin_bit_cast(bf16x8, f0);
      pbf[1] = __builtin_bit_cast(bf16x8, f1);
    }
    // V(t) (own 4) retired; K(t+1) (4) still in flight
    if (!last) { asm volatile("s_waitcnt vmcnt(4)" ::: "memory"); }
    else       { asm volatile("s_waitcnt vmcnt(0)" ::: "memory"); }
    __builtin_amdgcn_sched_barrier(0);
    __builtin_amdgcn_s_barrier();    // all waves' V(t) visible
    __builtin_amdgcn_sched_barrier(0);
    // O^T += V^T P^T
    __builtin_amdgcn_s_setprio(1);
#pragma unroll
    for (int kc = 0; kc < 2; kc++) {
      int sv = 2 * kc + h8;
      int sx = (sv ^ vxr) * 8;
      {
        bf16x8 vf = *(const bf16x8*)(Vs + (size_t)(0 * 32 + c32) * 32 + sx);
        O0 = mfma32(vf, pbf[kc], O0);
      }
      {
        bf16x8 vf = *(const bf16x8*)(Vs + (size_t)(1 * 32 + c32) * 32 + sx);
        O1 = mfma32(vf, pbf[kc], O1);
      }
      {
        bf16x8 vf = *(const bf16x8*)(Vs + (size_t)(2 * 32 + c32) * 32 + sx);
        O2 = mfma32(vf, pbf[kc], O2);
      }
      {
        bf16x8 vf = *(const bf16x8*)(Vs + (size_t)(3 * 32 + c32) * 32 + sx);
        O3 = mfma32(vf, pbf[kc], O3);
      }
    }
    __builtin_amdgcn_s_setprio(0);
    __builtin_amdgcn_sched_barrier(0);
    __builtin_amdgcn_s_barrier();    // all waves done reading Vs / Ks[cur]
    __builtin_amdgcn_sched_barrier(0);
    cur ^= 1;
  }
#undef STAGE_K
#undef STAGE_V
  // epilogue: raw partial O (f32) + (Mx, Ls)
  {
    float* Orow = Opart + (size_t)sp * 4194304 + (size_t)(qw0 + c32) * 4096 + h * 128;
#pragma unroll
    for (int a = 0; a < 4; a++) {
      f32x4 o0, o1, o2, o3;
#pragma unroll
      for (int b = 0; b < 4; b++) {
        o0[b] = O0[4 * a + b]; o1[b] = O1[4 * a + b];
        o2[b] = O2[4 * a + b]; o3[b] = O3[4 * a + b];
      }
      int d0 = 8 * a + 4 * h8;
      *(f32x4*)(Orow + d0) = o0;
      *(f32x4*)(Orow + 32 + d0) = o1;
      *(f32x4*)(Orow + 64 + d0) = o2;
      *(f32x4*)(Orow + 96 + d0) = o3;
    }
    if (h8 == 0) {
      float* mp = Ml + ((size_t)(sp * 32 + h) * 1024 + qw0 + c32) * 2;
      mp[0] = Mx; mp[1] = Ls;
    }
  }
}

// ---- combine the three KV-split parts -> ctxb bf16 (exp2-domain m) ----
__global__ __launch_bounds__(256) void attn_combine(const float* __restrict__ Opart,
    const float* __restrict__ Ml, u16* __restrict__ ctxb)
{
  int idx = blockIdx.x * 256 + threadIdx.x;  // 1048576
  int q = idx >> 10, c4 = idx & 1023;
  int col = c4 * 4, h = col >> 7;
  const float* m0p = Ml + ((size_t)h * 1024 + q) * 2;
  const float* m1p = Ml + ((size_t)(32 + h) * 1024 + q) * 2;
  const float* m2p = Ml + ((size_t)(64 + h) * 1024 + q) * 2;
  float m0 = m0p[0], l0 = m0p[1];
  float m1 = m1p[0], l1 = m1p[1];
  float m2 = m2p[0], l2 = m2p[1];
  float M = fmaxf(fmaxf(m0, m1), m2);
  float w0 = exp2f(m0 - M), w1 = exp2f(m1 - M), w2 = exp2f(m2 - M);
  float inv = 1.0f / (l0 * w0 + l1 * w1 + l2 * w2);
  f32x4 a = *(const f32x4*)(Opart + (size_t)q * 4096 + col);
  f32x4 b = *(const f32x4*)(Opart + 4194304 + (size_t)q * 4096 + col);
  f32x4 cc = *(const f32x4*)(Opart + 2 * 4194304 + (size_t)q * 4096 + col);
  u16x4 o;
#pragma unroll
  for (int i = 0; i < 4; i++)
    o[i] = f2bf((a[i] * w0 + b[i] * w1 + cc[i] * w2) * inv);
  *(u16x4*)(ctxb + (size_t)q * 4096 + col) = o;
}

extern "C" void kernel_launch(void* const* d_in, const int* in_sizes, int n_in,
                              void* d_out, int out_size, void* d_ws, size_t ws_size,
                              hipStream_t stream) {
  const float* x      = (const float*)d_in[0];
  const float* cosb   = (const float*)d_in[2];
  const float* sinb   = (const float*)d_in[3];
  const float* prev_k = (const float*)d_in[5];
  const float* prev_v = (const float*)d_in[6];
  const float* Wq     = (const float*)d_in[7];
  const float* Wk     = (const float*)d_in[8];
  const float* Wv     = (const float*)d_in[9];
  const float* Wo     = (const float*)d_in[10];

  // workspace layout (~144 MB)
  u16* Wt_proj = (u16*)d_ws;                                  // [6144][4096] bf16 (50.3MB)
  u16* Wt_out  = Wt_proj + (size_t)6144 * 4096;               // [4096][4096] bf16
  u16* xb      = Wt_out + (size_t)4096 * 4096;                // [1024][4096] bf16
  float* qkv   = (float*)(xb + (size_t)1024 * 4096);          // [1024][6144] f32
  u16* qb      = (u16*)(qkv + (size_t)1024 * 6144);           // [32][1024][128]
  u16* kbb     = qb + (size_t)32 * 1024 * 128;                // [8][4096][128]
  u16* vT      = kbb + (size_t)8 * 4096 * 128;                // [8][128][4096]
  u16* ctxb    = vT + (size_t)8 * 4096 * 128;                 // [1024][4096]
  // attn partials: Opart[3] ALIASES Wt_proj (exactly 50331648 B, dead after gemm1);
  // Ml ALIASES xb (dead after gemm1)
  float* Opart = (float*)d_ws;                                // [3][1024][4096] f32
  float* Ml    = (float*)xb;                                  // [3][32][1024][2] f32

  float* outp   = (float*)d_out;
  float* keys   = outp + (size_t)4194304;
  float* values = outp + (size_t)8388608;

  wtrans<<<4096, 256, 0, stream>>>(Wq, Wt_proj, 4096, 64, 0);
  wtrans<<<1024, 256, 0, stream>>>(Wk, Wt_proj, 1024, 16, 4096);
  wtrans<<<1024, 256, 0, stream>>>(Wv, Wt_proj, 1024, 16, 5120);
  wtrans<<<4096, 256, 0, stream>>>(Wo, Wt_out, 4096, 64, 0);
  cvt_bf16<<<4096, 256, 0, stream>>>(x, xb, 1048576);

  gemm_bt<<<768, 256, 0, stream>>>(xb, Wt_proj, qkv, 6144, 4096, 96);

  rope_q<<<2048, 256, 0, stream>>>(qkv, cosb, sinb, qb);
  rope_k<<<512, 256, 0, stream>>>(qkv, cosb, sinb, keys, kbb);
  copy_vnew<<<1024, 256, 0, stream>>>(qkv, values);
  prev_copy<<<3072, 256, 0, stream>>>(prev_k, prev_v, keys, values, kbb);
  vtrans<<<1024, 256, 0, stream>>>(prev_v, qkv, vT);

  attn_fwd<<<1536, 128, 0, stream>>>(qb, kbb, vT, Opart, Ml);
  attn_combine<<<4096, 256, 0, stream>>>(Opart, Ml, ctxb);

  gemm_bt<<<512, 256, 0, stream>>>(ctxb, Wt_out, outp, 4096, 4096, 64);
}

// Round 15
// 372.328 us; speedup vs baseline: 1.0699x; 1.0699x over previous
//
#include <hip/hip_runtime.h>
#include <hip/hip_bf16.h>

typedef unsigned short u16;
typedef unsigned int u32;
typedef __attribute__((ext_vector_type(4))) float f32x4;
typedef __attribute__((ext_vector_type(16))) float f32x16;
typedef __attribute__((ext_vector_type(8))) __bf16 bf16x8;
typedef __attribute__((ext_vector_type(4))) u16 u16x4;
typedef __attribute__((ext_vector_type(8))) u16 u16x8;
typedef __attribute__((ext_vector_type(4))) u32 u32x4;

#define START_POS 3072
#define NKV 4096
#define HD_ 128
#define SEQ 1024
#define DIN_ 4096
#define DQKV 6144

__device__ __forceinline__ void gll16(const void* g, void* l) {
  __builtin_amdgcn_global_load_lds((const __attribute__((address_space(1))) u32*)g,
                                   (__attribute__((address_space(3))) u32*)l, 16, 0, 0);
}
__device__ __forceinline__ u16 f2bf(float f) {
  u32 u = __builtin_bit_cast(u32, f);
  return (u16)((u + 0x7fffu + ((u >> 16) & 1u)) >> 16);
}
__device__ __forceinline__ u32 pack2bf(float a, float b) {
  __hip_bfloat162 t = __float22bfloat162_rn(float2{a, b});  // low=a, high=b, RNE
  u32 u; __builtin_memcpy(&u, &t, 4);
  return u;
}
__device__ __forceinline__ f32x4 mfma16(bf16x8 a, bf16x8 b, f32x4 c) {
  return __builtin_amdgcn_mfma_f32_16x16x32_bf16(a, b, c, 0, 0, 0);
}
__device__ __forceinline__ f32x16 mfma32(bf16x8 a, bf16x8 b, f32x16 c) {
  return __builtin_amdgcn_mfma_f32_32x32x16_bf16(a, b, c, 0, 0, 0);
}

// ---- transpose+convert W f32 [K=4096][N] -> Wt bf16 [N][4096] ----
__global__ __launch_bounds__(256) void wtrans(const float* __restrict__ W,
    u16* __restrict__ Wt, int N, int ntn, int row_off)
{
  __shared__ float T[64][68];
  int bid = blockIdx.x;
  int nt = bid % ntn, kt = bid / ntn;
  int t = threadIdx.x;
  int kl = t >> 4, nl4 = (t & 15) << 2;
#pragma unroll
  for (int r = 0; r < 4; r++) {
    int row = r * 16 + kl;
    f32x4 v = *(const f32x4*)(W + (size_t)(kt * 64 + row) * N + nt * 64 + nl4);
    T[row][nl4] = v[0]; T[row][nl4 + 1] = v[1]; T[row][nl4 + 2] = v[2]; T[row][nl4 + 3] = v[3];
  }
  __syncthreads();
  int nl = t >> 2, k0 = (t & 3) << 4;
  u16x8 lo, hi;
#pragma unroll
  for (int j = 0; j < 8; j++) lo[j] = f2bf(T[k0 + j][nl]);
#pragma unroll
  for (int j = 0; j < 8; j++) hi[j] = f2bf(T[k0 + 8 + j][nl]);
  u16* dst = Wt + (size_t)(row_off + nt * 64 + nl) * 4096 + kt * 64 + k0;
  *(u16x8*)dst = lo;
  *(u16x8*)(dst + 8) = hi;
}

// ---- f32 -> bf16 convert ----
__global__ __launch_bounds__(256) void cvt_bf16(const float* __restrict__ src,
    u16* __restrict__ dst, int n4)
{
  int i = blockIdx.x * 256 + threadIdx.x;
  if (i >= n4) return;
  f32x4 v = *(const f32x4*)(src + (size_t)i * 4);
  u16x4 o;
#pragma unroll
  for (int j = 0; j < 4; j++) o[j] = f2bf(v[j]);
  *(u16x4*)(dst + (size_t)i * 4) = o;
}

// ---- bf16 GEMM v3: 128x64 tile, BK=32, dbuf 2-phase + T2 XOR swizzle (4-slot) ----
__global__ __launch_bounds__(256) void gemm_bt(
    const u16* __restrict__ A, const u16* __restrict__ Bt,
    float* __restrict__ C, int N, int K, int nbx)
{
  __shared__ u16 As[2 * 128 * 32];
  __shared__ u16 Bs[2 * 64 * 32];
  int nwg = (int)gridDim.x;
  int orig = blockIdx.x;
  int q8 = nwg >> 3, r8 = nwg & 7;
  int xcd = orig & 7, jj = orig >> 3;
  int wgid = (xcd < r8 ? xcd * (q8 + 1) : r8 * (q8 + 1) + (xcd - r8) * q8) + jj;
  int by = wgid / nbx, bx = wgid % nbx;
  int tid = threadIdx.x, lane = tid & 63, wid = tid >> 6;
  int wr = wid >> 1, wc = wid & 1;
  int c = lane & 15, hh = lane >> 4;
  int lrow = wid * 16 + (lane >> 2);       // 0..63
  // T2 swizzle: LDS row = 64B = 4 slots of 16B; stage source k-chunk = sl ^ (row&3),
  // read slot = hh ^ (row&3). Linear LDS dest (rule #21), involution on both sides.
  int ksl = (((lane & 3) ^ ((lane >> 2) & 3)) << 3);
  const u16* aS0 = A + (size_t)(by * 128 + lrow) * K + ksl;
  const u16* bS0 = Bt + (size_t)(bx * 64 + lrow) * K + ksl;

#define GSTAGE(buf, kk) do { \
  gll16(aS0 + (kk), As + (buf) * 4096 + wid * 512); \
  gll16(aS0 + (size_t)64 * K + (kk), As + (buf) * 4096 + 2048 + wid * 512); \
  gll16(bS0 + (kk), Bs + (buf) * 2048 + wid * 512); \
} while (0)

  f32x4 acc[4][2] = {};
  int nk = K >> 5;
  int cur = 0;
  int swz = hh ^ (c & 3);                  // read slot (per-lane constant)
  GSTAGE(0, 0);
  __syncthreads();                          // tile 0 resident
  for (int kt = 0; kt < nk; kt++) {
    if (kt + 1 < nk) GSTAGE(cur ^ 1, (kt + 1) * 32);  // prefetch next
    const u16* Ab = As + cur * 4096;
    const u16* Bb = Bs + cur * 2048;
    bf16x8 af[4], bf[2];
#pragma unroll
    for (int i = 0; i < 4; i++)
      af[i] = *(const bf16x8*)(Ab + (wr * 64 + i * 16 + c) * 32 + swz * 8);
#pragma unroll
    for (int i = 0; i < 2; i++)
      bf[i] = *(const bf16x8*)(Bb + (wc * 32 + i * 16 + c) * 32 + swz * 8);
    __builtin_amdgcn_s_setprio(1);
#pragma unroll
    for (int mi = 0; mi < 4; mi++)
#pragma unroll
      for (int ni = 0; ni < 2; ni++)
        acc[mi][ni] = mfma16(af[mi], bf[ni], acc[mi][ni]);
    __builtin_amdgcn_s_setprio(0);
    __syncthreads();
    cur ^= 1;
  }
#undef GSTAGE
  int row0 = by * 128 + wr * 64 + hh * 4;
  int col0 = bx * 64 + wc * 32 + c;
#pragma unroll
  for (int mi = 0; mi < 4; mi++)
#pragma unroll
    for (int ni = 0; ni < 2; ni++)
#pragma unroll
      for (int i = 0; i < 4; i++)
        C[(size_t)(row0 + mi * 16 + i) * N + col0 + ni * 16] = acc[mi][ni][i];
}

// ---- RoPE on q part of qkv -> qb bf16 [32][1024][128], PRE-SCALED by log2(e)/sqrt(128) ----
__global__ __launch_bounds__(256) void rope_q(const float* __restrict__ qkv,
    const float* __restrict__ cosb, const float* __restrict__ sinb, u16* __restrict__ qb)
{
  const float C2 = 0.12751744f;
  int tid = blockIdx.x * 256 + threadIdx.x;  // 524288
  int dq = tid & 15, h = (tid >> 4) & 31, s = tid >> 9;
  int d = dq << 2;
  const float* base = qkv + (size_t)s * DQKV + h * HD_ + d;
  f32x4 a = *(const f32x4*)base;
  f32x4 b2 = *(const f32x4*)(base + 64);
  f32x4 cc = *(const f32x4*)(cosb + (size_t)(START_POS + s) * HD_ + d);
  f32x4 sn = *(const f32x4*)(sinb + (size_t)(START_POS + s) * HD_ + d);
  u16x4 o1, o2;
#pragma unroll
  for (int i = 0; i < 4; i++) {
    o1[i] = f2bf((a[i] * cc[i] - b2[i] * sn[i]) * C2);
    o2[i] = f2bf((b2[i] * cc[i] + a[i] * sn[i]) * C2);
  }
  u16* dst = qb + ((size_t)h * SEQ + s) * HD_ + d;
  *(u16x4*)dst = o1;
  *(u16x4*)(dst + 64) = o2;
}

// ---- RoPE on k part -> keys f32 output (pos>=3072) + kb bf16 ----
__global__ __launch_bounds__(256) void rope_k(const float* __restrict__ qkv,
    const float* __restrict__ cosb, const float* __restrict__ sinb,
    float* __restrict__ keys, u16* __restrict__ kbb)
{
  int tid = blockIdx.x * 256 + threadIdx.x;  // 131072
  int dq = tid & 15, g = (tid >> 4) & 7, s = tid >> 7;
  int d = dq << 2;
  const float* base = qkv + (size_t)s * DQKV + DIN_ + g * HD_ + d;
  f32x4 a = *(const f32x4*)base;
  f32x4 b2 = *(const f32x4*)(base + 64);
  f32x4 cc = *(const f32x4*)(cosb + (size_t)(START_POS + s) * HD_ + d);
  f32x4 sn = *(const f32x4*)(sinb + (size_t)(START_POS + s) * HD_ + d);
  f32x4 o1, o2;
  u16x4 p1, p2;
#pragma unroll
  for (int i = 0; i < 4; i++) {
    o1[i] = a[i] * cc[i] - b2[i] * sn[i];
    o2[i] = b2[i] * cc[i] + a[i] * sn[i];
    p1[i] = f2bf(o1[i]);
    p2[i] = f2bf(o2[i]);
  }
  size_t off = ((size_t)g * NKV + START_POS + s) * HD_ + d;
  *(f32x4*)(keys + off) = o1;
  *(f32x4*)(keys + off + 64) = o2;
  *(u16x4*)(kbb + off) = p1;
  *(u16x4*)(kbb + off + 64) = p2;
}

// ---- copy v part -> values f32 output (pos>=3072) ----
__global__ __launch_bounds__(256) void copy_vnew(const float* __restrict__ qkv,
    float* __restrict__ values)
{
  int tid = blockIdx.x * 256 + threadIdx.x;  // 262144
  int dq = tid & 31, g = (tid >> 5) & 7, s = tid >> 8;
  int d = dq << 2;
  f32x4 v = *(const f32x4*)(qkv + (size_t)s * DQKV + DIN_ + 1024 + g * HD_ + d);
  *(f32x4*)(values + ((size_t)g * NKV + START_POS + s) * HD_ + d) = v;
}

// ---- copy prev_k/prev_v -> keys/values f32 outputs + kb bf16 ----
__global__ __launch_bounds__(256) void prev_copy(const float* __restrict__ pk,
    const float* __restrict__ pv, float* __restrict__ keys, float* __restrict__ values,
    u16* __restrict__ kbb)
{
  int idx = blockIdx.x * 256 + threadIdx.x;  // 786432 quads
  int d4 = idx & 31;
  int rest = idx >> 5;
  int p = rest % 3072, g = rest / 3072;
  f32x4 kq = *(const f32x4*)(pk + (size_t)idx * 4);
  f32x4 vq = *(const f32x4*)(pv + (size_t)idx * 4);
  size_t off = ((size_t)g * NKV + p) * HD_ + d4 * 4;
  *(f32x4*)(keys + off) = kq;
  *(f32x4*)(values + off) = vq;
  u16x4 kb4;
#pragma unroll
  for (int i = 0; i < 4; i++) kb4[i] = f2bf(kq[i]);
  *(u16x4*)(kbb + off) = kb4;
}

// ---- build vT bf16 [8][128][4096] from prev_v (pos<3072) / qkv v-cols ----
__global__ __launch_bounds__(256) void vtrans(const float* __restrict__ pv,
    const float* __restrict__ qkv, u16* __restrict__ vT)
{
  __shared__ float T[64][68];
  int bid = blockIdx.x;  // 1024 = g(8) * pt(64) * dt(2)
  int dt = bid & 1, pt = (bid >> 1) & 63, g = bid >> 7;
  int t = threadIdx.x;
  int pl = t >> 4, dl4 = (t & 15) << 2;
#pragma unroll
  for (int r = 0; r < 4; r++) {
    int row = r * 16 + pl;
    int pos = pt * 64 + row;
    f32x4 v;
    if (pos < START_POS)
      v = *(const f32x4*)(pv + ((size_t)g * START_POS + pos) * HD_ + dt * 64 + dl4);
    else
      v = *(const f32x4*)(qkv + (size_t)(pos - START_POS) * DQKV + 5120 + g * HD_ + dt * 64 + dl4);
    T[row][dl4] = v[0]; T[row][dl4 + 1] = v[1]; T[row][dl4 + 2] = v[2]; T[row][dl4 + 3] = v[3];
  }
  __syncthreads();
  int dl = t >> 2, p0 = (t & 3) << 4;
  u16x8 lo, hi;
#pragma unroll
  for (int j = 0; j < 8; j++) lo[j] = f2bf(T[p0 + j][dl]);
#pragma unroll
  for (int j = 0; j < 8; j++) hi[j] = f2bf(T[p0 + 8 + j][dl]);
  u16* dst = vT + ((size_t)g * HD_ + dt * 64 + dl) * NKV + pt * 64 + p0;
  *(u16x8*)dst = lo;
  *(u16x8*)(dst + 8) = hi;
}

// ---- flash attention v5e: r13-verified v5d structure + C2 folded into Q ----
__global__ __launch_bounds__(128, 2) void attn_fwd(
    const u16* __restrict__ qb, const u16* __restrict__ kb,
    const u16* __restrict__ vT, float* __restrict__ Opart, float* __restrict__ Ml)
{
  __shared__ u16 Ks[2 * 32 * 128];   // [buf][kv 32][d 128], 16B-slot XOR swizzle
  __shared__ u16 Vs[2 * 128 * 32];   // [buf][d 128][kv 32], slot^((d>>1)&3) swizzle
  int bid = blockIdx.x;
  int g = bid & 7, j = bid >> 3;     // XCD x owns KV group g=x; j in [0,128)
  int sp = j >> 6, jj = j & 63;
  int h = g * 4 + (jj >> 4), qt = jj & 15;
  int tid = threadIdx.x, lane = tid & 63, w = tid >> 6;
  int c32 = lane & 31, h8 = lane >> 5;
  int qw0 = qt * 64 + w * 32;
  bf16x8 Qf[8];
#pragma unroll
  for (int dc = 0; dc < 8; dc++)
    Qf[dc] = *(const bf16x8*)(qb + ((size_t)(h * 1024 + qw0 + c32)) * 128 + dc * 16 + h8 * 8);
  f32x16 O0 = {}, O1 = {}, O2 = {}, O3 = {};
  float Mx = -1e30f, Ls = 0.f;
  // balanced split: sp0 = [0, 49+qt) (provably unmasked), sp1 = [49+qt, 98+2qt)
  int t0 = sp ? (49 + qt) : 0;
  int t1 = sp ? (98 + 2 * qt) : (49 + qt);

#define STAGE_KV(tt, bo) do { \
  _Pragma("unroll") \
  for (int r = 0; r < 4; r++) { \
    int s = w * 256 + r * 64 + lane; \
    int krow = s >> 4, sl = s & 15; \
    gll16(kb + ((size_t)(g * 4096 + (tt) * 32 + krow)) * 128 + (sl ^ (krow & 7)) * 8, \
          Ks + (bo) + (w * 256 + r * 64) * 8); \
    int d = s >> 2, sl2 = s & 3; \
    gll16(vT + ((size_t)(g * 128 + d)) * 4096 + (tt) * 32 + (sl2 ^ ((d >> 1) & 3)) * 8, \
          Vs + (bo) + (w * 256 + r * 64) * 8); \
  } \
} while (0)

  int cur = 0;
  STAGE_KV(t0, 0);
  __syncthreads();
  int vxr = (c32 >> 1) & 3;  // ((32*db + c32)>>1)&3 == (c32>>1)&3 for all db
  for (int t = t0; t < t1; t++) {
    if (t + 1 < t1) STAGE_KV(t + 1, (cur ^ 1) * 4096);
    const u16* Kb = Ks + cur * 4096;
    const u16* Vb = Vs + cur * 4096;
    // S^T = K Q^T : two independent accumulator chains
    f32x16 S0 = {}, Sb = {};
    __builtin_amdgcn_s_setprio(1);
#pragma unroll
    for (int dc = 0; dc < 8; dc += 2) {
      int sxA = (2 * dc + h8) ^ (c32 & 7);
      int sxB = (2 * dc + 2 + h8) ^ (c32 & 7);
      bf16x8 kA = *(const bf16x8*)(Kb + (size_t)c32 * 128 + sxA * 8);
      bf16x8 kB = *(const bf16x8*)(Kb + (size_t)c32 * 128 + sxB * 8);
      S0 = mfma32(kA, Qf[dc], S0);
      Sb = mfma32(kB, Qf[dc + 1], Sb);
    }
    __builtin_amdgcn_s_setprio(0);
#pragma unroll
    for (int r = 0; r < 16; r++) S0[r] += Sb[r];
    // causal mask (only sp=1 blocks near diagonal); S in exp2-domain units
    if (t * 32 + 31 > START_POS + qw0) {
      int qa = START_POS + qw0 + c32;
#pragma unroll
      for (int r = 0; r < 16; r++) {
        int kvo = t * 32 + (r & 3) + 8 * (r >> 2) + 4 * h8;
        if (kvo > qa) S0[r] = -1e30f;
      }
    }
    // row max: 15-op tree + cross-half via shfl_xor(32)
    float tm[16];
#pragma unroll
    for (int r = 0; r < 16; r++) tm[r] = S0[r];
#pragma unroll
    for (int sft = 8; sft >= 1; sft >>= 1)
#pragma unroll
      for (int r = 0; r < sft; r++) tm[r] = fmaxf(tm[r], tm[r + sft]);
    float full = fmaxf(tm[0], __shfl_xor(tm[0], 32));
    // defer-max (T13), exp2-domain threshold 8
    if (!__all(full <= Mx + 8.0f)) {
      float Mn = fmaxf(Mx, full);
      float al = exp2f(Mx - Mn);
      Mx = Mn;
      Ls *= al;
#pragma unroll
      for (int r = 0; r < 16; r++) { O0[r] *= al; O1[r] *= al; O2[r] *= al; O3[r] *= al; }
    }
#pragma unroll
    for (int r = 0; r < 16; r++) S0[r] = exp2f(S0[r] - Mx);
    // row sum
    float ts[16];
#pragma unroll
    for (int r = 0; r < 16; r++) ts[r] = S0[r];
#pragma unroll
    for (int sft = 8; sft >= 1; sft >>= 1)
#pragma unroll
      for (int r = 0; r < sft; r++) ts[r] = ts[r] + ts[r + sft];
    Ls += ts[0] + __shfl_xor(ts[0], 32);
    // pack P + cross-half exchange (verified routing)
    u32 pk0[8], x0[8];
#pragma unroll
    for (int m = 0; m < 8; m++) pk0[m] = pack2bf(S0[2 * m], S0[2 * m + 1]);
#pragma unroll
    for (int m = 0; m < 8; m++) x0[m] = __shfl_xor(pk0[m], 32);
    bf16x8 pbf[2];
    {
      u32x4 f0 = { h8 ? x0[2] : pk0[0], h8 ? x0[3] : pk0[1],
                   h8 ? pk0[2] : x0[0], h8 ? pk0[3] : x0[1] };
      u32x4 f1 = { h8 ? x0[6] : pk0[4], h8 ? x0[7] : pk0[5],
                   h8 ? pk0[6] : x0[4], h8 ? pk0[7] : x0[5] };
      pbf[0] = __builtin_bit_cast(bf16x8, f0);
      pbf[1] = __builtin_bit_cast(bf16x8, f1);
    }
    // O^T += V^T P^T
    __builtin_amdgcn_s_setprio(1);
#pragma unroll
    for (int kc = 0; kc < 2; kc++) {
      int sv = 2 * kc + h8;
      int sx = (sv ^ vxr) * 8;
      {
        bf16x8 vf = *(const bf16x8*)(Vb + (size_t)(0 * 32 + c32) * 32 + sx);
        O0 = mfma32(vf, pbf[kc], O0);
      }
      {
        bf16x8 vf = *(const bf16x8*)(Vb + (size_t)(1 * 32 + c32) * 32 + sx);
        O1 = mfma32(vf, pbf[kc], O1);
      }
      {
        bf16x8 vf = *(const bf16x8*)(Vb + (size_t)(2 * 32 + c32) * 32 + sx);
        O2 = mfma32(vf, pbf[kc], O2);
      }
      {
        bf16x8 vf = *(const bf16x8*)(Vb + (size_t)(3 * 32 + c32) * 32 + sx);
        O3 = mfma32(vf, pbf[kc], O3);
      }
    }
    __builtin_amdgcn_s_setprio(0);
    __syncthreads();
    cur ^= 1;
  }
#undef STAGE_KV
  // epilogue: raw partial O (f32) + (Mx, Ls)
  {
    float* Orow = Opart + (size_t)sp * 4194304 + (size_t)(qw0 + c32) * 4096 + h * 128;
#pragma unroll
    for (int a = 0; a < 4; a++) {
      f32x4 o0, o1, o2, o3;
#pragma unroll
      for (int b = 0; b < 4; b++) {
        o0[b] = O0[4 * a + b]; o1[b] = O1[4 * a + b];
        o2[b] = O2[4 * a + b]; o3[b] = O3[4 * a + b];
      }
      int d0 = 8 * a + 4 * h8;
      *(f32x4*)(Orow + d0) = o0;
      *(f32x4*)(Orow + 32 + d0) = o1;
      *(f32x4*)(Orow + 64 + d0) = o2;
      *(f32x4*)(Orow + 96 + d0) = o3;
    }
    if (h8 == 0) {
      float* mp = Ml + ((size_t)(sp * 32 + h) * 1024 + qw0 + c32) * 2;
      mp[0] = Mx; mp[1] = Ls;
    }
  }
}

// ---- combine the two KV-split halves -> ctxb bf16 (exp2-domain m) ----
__global__ __launch_bounds__(256) void attn_combine(const float* __restrict__ Opart,
    const float* __restrict__ Ml, u16* __restrict__ ctxb)
{
  int idx = blockIdx.x * 256 + threadIdx.x;  // 1048576
  int q = idx >> 10, c4 = idx & 1023;
  int col = c4 * 4, h = col >> 7;
  const float* m0p = Ml + ((size_t)h * 1024 + q) * 2;
  const float* m1p = Ml + ((size_t)(32 + h) * 1024 + q) * 2;
  float m0 = m0p[0], l0 = m0p[1];
  float m1 = m1p[0], l1 = m1p[1];
  float M = fmaxf(m0, m1);
  float w0 = exp2f(m0 - M);
  float w1 = exp2f(m1 - M);
  float inv = 1.0f / (l0 * w0 + l1 * w1);
  f32x4 a = *(const f32x4*)(Opart + (size_t)q * 4096 + col);
  f32x4 b = *(const f32x4*)(Opart + 4194304 + (size_t)q * 4096 + col);
  u16x4 o;
#pragma unroll
  for (int i = 0; i < 4; i++) o[i] = f2bf((a[i] * w0 + b[i] * w1) * inv);
  *(u16x4*)(ctxb + (size_t)q * 4096 + col) = o;
}

extern "C" void kernel_launch(void* const* d_in, const int* in_sizes, int n_in,
                              void* d_out, int out_size, void* d_ws, size_t ws_size,
                              hipStream_t stream) {
  const float* x      = (const float*)d_in[0];
  const float* cosb   = (const float*)d_in[2];
  const float* sinb   = (const float*)d_in[3];
  const float* prev_k = (const float*)d_in[5];
  const float* prev_v = (const float*)d_in[6];
  const float* Wq     = (const float*)d_in[7];
  const float* Wk     = (const float*)d_in[8];
  const float* Wv     = (const float*)d_in[9];
  const float* Wo     = (const float*)d_in[10];

  // workspace layout (~144 MB)
  u16* Wt_proj = (u16*)d_ws;                                  // [6144][4096] bf16 (50.3MB)
  u16* Wt_out  = Wt_proj + (size_t)6144 * 4096;               // [4096][4096] bf16
  u16* xb      = Wt_out + (size_t)4096 * 4096;                // [1024][4096] bf16
  float* qkv   = (float*)(xb + (size_t)1024 * 4096);          // [1024][6144] f32
  u16* qb      = (u16*)(qkv + (size_t)1024 * 6144);           // [32][1024][128]
  u16* kbb     = qb + (size_t)32 * 1024 * 128;                // [8][4096][128]
  u16* vT      = kbb + (size_t)8 * 4096 * 128;                // [8][128][4096]
  u16* ctxb    = vT + (size_t)8 * 4096 * 128;                 // [1024][4096]
  // attn partials ALIAS Wt_proj (dead after gemm1; rewritten each call): 32.5MB < 50.3MB
  float* Opart = (float*)d_ws;                                // [2][1024][4096] f32
  float* Ml    = Opart + (size_t)2 * 1024 * 4096;             // [2][32][1024][2] f32

  float* outp   = (float*)d_out;
  float* keys   = outp + (size_t)4194304;
  float* values = outp + (size_t)8388608;

  wtrans<<<4096, 256, 0, stream>>>(Wq, Wt_proj, 4096, 64, 0);
  wtrans<<<1024, 256, 0, stream>>>(Wk, Wt_proj, 1024, 16, 4096);
  wtrans<<<1024, 256, 0, stream>>>(Wv, Wt_proj, 1024, 16, 5120);
  wtrans<<<4096, 256, 0, stream>>>(Wo, Wt_out, 4096, 64, 0);
  cvt_bf16<<<4096, 256, 0, stream>>>(x, xb, 1048576);

  gemm_bt<<<768, 256, 0, stream>>>(xb, Wt_proj, qkv, 6144, 4096, 96);

  rope_q<<<2048, 256, 0, stream>>>(qkv, cosb, sinb, qb);
  rope_k<<<512, 256, 0, stream>>>(qkv, cosb, sinb, keys, kbb);
  copy_vnew<<<1024, 256, 0, stream>>>(qkv, values);
  prev_copy<<<3072, 256, 0, stream>>>(prev_k, prev_v, keys, values, kbb);
  vtrans<<<1024, 256, 0, stream>>>(prev_v, qkv, vT);

  attn_fwd<<<1024, 128, 0, stream>>>(qb, kbb, vT, Opart, Ml);
  attn_combine<<<4096, 256, 0, stream>>>(Opart, Ml, ctxb);

  gemm_bt<<<512, 256, 0, stream>>>(ctxb, Wt_out, outp, 4096, 4096, 64);
}

// Round 16
// 345.770 us; speedup vs baseline: 1.1521x; 1.0768x over previous
//
#include <hip/hip_runtime.h>
#include <hip/hip_bf16.h>

typedef unsigned short u16;
typedef unsigned int u32;
typedef __attribute__((ext_vector_type(4))) float f32x4;
typedef __attribute__((ext_vector_type(16))) float f32x16;
typedef __attribute__((ext_vector_type(8))) __bf16 bf16x8;
typedef __attribute__((ext_vector_type(4))) u16 u16x4;
typedef __attribute__((ext_vector_type(8))) u16 u16x8;
typedef __attribute__((ext_vector_type(4))) u32 u32x4;

#define START_POS 3072
#define NKV 4096
#define HD_ 128
#define SEQ 1024
#define DIN_ 4096
#define DQKV 6144

__device__ __forceinline__ void gll16(const void* g, void* l) {
  __builtin_amdgcn_global_load_lds((const __attribute__((address_space(1))) u32*)g,
                                   (__attribute__((address_space(3))) u32*)l, 16, 0, 0);
}
__device__ __forceinline__ u16 f2bf(float f) {
  u32 u = __builtin_bit_cast(u32, f);
  return (u16)((u + 0x7fffu + ((u >> 16) & 1u)) >> 16);
}
__device__ __forceinline__ u32 pack2bf(float a, float b) {
  __hip_bfloat162 t = __float22bfloat162_rn(float2{a, b});  // low=a, high=b, RNE
  u32 u; __builtin_memcpy(&u, &t, 4);
  return u;
}
__device__ __forceinline__ f32x4 mfma16(bf16x8 a, bf16x8 b, f32x4 c) {
  return __builtin_amdgcn_mfma_f32_16x16x32_bf16(a, b, c, 0, 0, 0);
}
__device__ __forceinline__ f32x16 mfma32(bf16x8 a, bf16x8 b, f32x16 c) {
  return __builtin_amdgcn_mfma_f32_32x32x16_bf16(a, b, c, 0, 0, 0);
}

// ---- transpose+convert W f32 [K=4096][N] -> Wt bf16 [N][4096] ----
__global__ __launch_bounds__(256) void wtrans(const float* __restrict__ W,
    u16* __restrict__ Wt, int N, int ntn, int row_off)
{
  __shared__ float T[64][68];
  int bid = blockIdx.x;
  int nt = bid % ntn, kt = bid / ntn;
  int t = threadIdx.x;
  int kl = t >> 4, nl4 = (t & 15) << 2;
#pragma unroll
  for (int r = 0; r < 4; r++) {
    int row = r * 16 + kl;
    f32x4 v = *(const f32x4*)(W + (size_t)(kt * 64 + row) * N + nt * 64 + nl4);
    T[row][nl4] = v[0]; T[row][nl4 + 1] = v[1]; T[row][nl4 + 2] = v[2]; T[row][nl4 + 3] = v[3];
  }
  __syncthreads();
  int nl = t >> 2, k0 = (t & 3) << 4;
  u16x8 lo, hi;
#pragma unroll
  for (int j = 0; j < 8; j++) lo[j] = f2bf(T[k0 + j][nl]);
#pragma unroll
  for (int j = 0; j < 8; j++) hi[j] = f2bf(T[k0 + 8 + j][nl]);
  u16* dst = Wt + (size_t)(row_off + nt * 64 + nl) * 4096 + kt * 64 + k0;
  *(u16x8*)dst = lo;
  *(u16x8*)(dst + 8) = hi;
}

// ---- f32 -> bf16 convert ----
__global__ __launch_bounds__(256) void cvt_bf16(const float* __restrict__ src,
    u16* __restrict__ dst, int n4)
{
  int i = blockIdx.x * 256 + threadIdx.x;
  if (i >= n4) return;
  f32x4 v = *(const f32x4*)(src + (size_t)i * 4);
  u16x4 o;
#pragma unroll
  for (int j = 0; j < 4; j++) o[j] = f2bf(v[j]);
  *(u16x4*)(dst + (size_t)i * 4) = o;
}

// ---- bf16 GEMM v4: 128x64 tile, BK=64, dbuf 2-phase, T2 swizzle (8-slot rows) ----
// 16 MFMA + 6 staging loads per barrier (2x the BK=32 density), 64 K-steps.
__global__ __launch_bounds__(256) void gemm_bt(
    const u16* __restrict__ A, const u16* __restrict__ Bt,
    float* __restrict__ C, int N, int K, int nbx)
{
  __shared__ u16 As[2 * 128 * 64];   // 32KB
  __shared__ u16 Bs[2 * 64 * 64];    // 16KB
  int nwg = (int)gridDim.x;
  int orig = blockIdx.x;
  int q8 = nwg >> 3, r8 = nwg & 7;
  int xcd = orig & 7, jj = orig >> 3;
  int wgid = (xcd < r8 ? xcd * (q8 + 1) : r8 * (q8 + 1) + (xcd - r8) * q8) + jj;
  int by = wgid / nbx, bx = wgid % nbx;
  int tid = threadIdx.x, lane = tid & 63, wid = tid >> 6;
  int wr = wid >> 1, wc = wid & 1;
  int c = lane & 15, hh = lane >> 4;
  // staging: lane covers row chunk (lane>>3) of 8-row group, source k-chunk
  // (lane&7)^(lane>>3)  (involution with LDS slot = lane&7; row&7 = lane>>3)
  int srow = lane >> 3;
  int schunk = ((lane & 7) ^ srow) << 3;
  const u16* aS0 = A + (size_t)(by * 128 + wid * 32 + srow) * K + schunk;
  const u16* bS0 = Bt + (size_t)(bx * 64 + wid * 16 + srow) * K + schunk;

#define GSTAGE(buf, kk) do { \
  _Pragma("unroll") \
  for (int r = 0; r < 4; r++) \
    gll16(aS0 + (size_t)r * 8 * K + (kk), As + (buf) * 8192 + (wid * 32 + r * 8) * 64); \
  _Pragma("unroll") \
  for (int r = 0; r < 2; r++) \
    gll16(bS0 + (size_t)r * 8 * K + (kk), Bs + (buf) * 4096 + (wid * 16 + r * 8) * 64); \
} while (0)

  f32x4 acc[4][2] = {};
  int nk = K >> 6;
  int cur = 0;
  int rsl = c & 7;                   // row&7 for all fragment rows (i*16 keeps low 3 bits)
  GSTAGE(0, 0);
  __syncthreads();                   // tile 0 resident
  for (int kt = 0; kt < nk; kt++) {
    if (kt + 1 < nk) GSTAGE(cur ^ 1, (kt + 1) * 64);  // prefetch next
    const u16* Ab = As + cur * 8192;
    const u16* Bb = Bs + cur * 4096;
#pragma unroll
    for (int kk = 0; kk < 2; kk++) {
      int slot = ((kk * 4 + hh) ^ rsl) * 8;
      bf16x8 af[4], bf[2];
#pragma unroll
      for (int i = 0; i < 4; i++)
        af[i] = *(const bf16x8*)(Ab + (wr * 64 + i * 16 + c) * 64 + slot);
#pragma unroll
      for (int i = 0; i < 2; i++)
        bf[i] = *(const bf16x8*)(Bb + (wc * 32 + i * 16 + c) * 64 + slot);
      __builtin_amdgcn_s_setprio(1);
#pragma unroll
      for (int mi = 0; mi < 4; mi++)
#pragma unroll
        for (int ni = 0; ni < 2; ni++)
          acc[mi][ni] = mfma16(af[mi], bf[ni], acc[mi][ni]);
      __builtin_amdgcn_s_setprio(0);
    }
    __syncthreads();                 // prefetch landed + all waves done with cur
    cur ^= 1;
  }
#undef GSTAGE
  int row0 = by * 128 + wr * 64 + hh * 4;
  int col0 = bx * 64 + wc * 32 + c;
#pragma unroll
  for (int mi = 0; mi < 4; mi++)
#pragma unroll
    for (int ni = 0; ni < 2; ni++)
#pragma unroll
      for (int i = 0; i < 4; i++)
        C[(size_t)(row0 + mi * 16 + i) * N + col0 + ni * 16] = acc[mi][ni][i];
}

// ---- RoPE on q part of qkv -> qb bf16 [32][1024][128], PRE-SCALED by log2(e)/sqrt(128) ----
__global__ __launch_bounds__(256) void rope_q(const float* __restrict__ qkv,
    const float* __restrict__ cosb, const float* __restrict__ sinb, u16* __restrict__ qb)
{
  const float C2 = 0.12751744f;
  int tid = blockIdx.x * 256 + threadIdx.x;  // 524288
  int dq = tid & 15, h = (tid >> 4) & 31, s = tid >> 9;
  int d = dq << 2;
  const float* base = qkv + (size_t)s * DQKV + h * HD_ + d;
  f32x4 a = *(const f32x4*)base;
  f32x4 b2 = *(const f32x4*)(base + 64);
  f32x4 cc = *(const f32x4*)(cosb + (size_t)(START_POS + s) * HD_ + d);
  f32x4 sn = *(const f32x4*)(sinb + (size_t)(START_POS + s) * HD_ + d);
  u16x4 o1, o2;
#pragma unroll
  for (int i = 0; i < 4; i++) {
    o1[i] = f2bf((a[i] * cc[i] - b2[i] * sn[i]) * C2);
    o2[i] = f2bf((b2[i] * cc[i] + a[i] * sn[i]) * C2);
  }
  u16* dst = qb + ((size_t)h * SEQ + s) * HD_ + d;
  *(u16x4*)dst = o1;
  *(u16x4*)(dst + 64) = o2;
}

// ---- RoPE on k part -> keys f32 output (pos>=3072) + kb bf16 ----
__global__ __launch_bounds__(256) void rope_k(const float* __restrict__ qkv,
    const float* __restrict__ cosb, const float* __restrict__ sinb,
    float* __restrict__ keys, u16* __restrict__ kbb)
{
  int tid = blockIdx.x * 256 + threadIdx.x;  // 131072
  int dq = tid & 15, g = (tid >> 4) & 7, s = tid >> 7;
  int d = dq << 2;
  const float* base = qkv + (size_t)s * DQKV + DIN_ + g * HD_ + d;
  f32x4 a = *(const f32x4*)base;
  f32x4 b2 = *(const f32x4*)(base + 64);
  f32x4 cc = *(const f32x4*)(cosb + (size_t)(START_POS + s) * HD_ + d);
  f32x4 sn = *(const f32x4*)(sinb + (size_t)(START_POS + s) * HD_ + d);
  f32x4 o1, o2;
  u16x4 p1, p2;
#pragma unroll
  for (int i = 0; i < 4; i++) {
    o1[i] = a[i] * cc[i] - b2[i] * sn[i];
    o2[i] = b2[i] * cc[i] + a[i] * sn[i];
    p1[i] = f2bf(o1[i]);
    p2[i] = f2bf(o2[i]);
  }
  size_t off = ((size_t)g * NKV + START_POS + s) * HD_ + d;
  *(f32x4*)(keys + off) = o1;
  *(f32x4*)(keys + off + 64) = o2;
  *(u16x4*)(kbb + off) = p1;
  *(u16x4*)(kbb + off + 64) = p2;
}

// ---- copy v part -> values f32 output (pos>=3072) ----
__global__ __launch_bounds__(256) void copy_vnew(const float* __restrict__ qkv,
    float* __restrict__ values)
{
  int tid = blockIdx.x * 256 + threadIdx.x;  // 262144
  int dq = tid & 31, g = (tid >> 5) & 7, s = tid >> 8;
  int d = dq << 2;
  f32x4 v = *(const f32x4*)(qkv + (size_t)s * DQKV + DIN_ + 1024 + g * HD_ + d);
  *(f32x4*)(values + ((size_t)g * NKV + START_POS + s) * HD_ + d) = v;
}

// ---- copy prev_k/prev_v -> keys/values f32 outputs + kb bf16 ----
__global__ __launch_bounds__(256) void prev_copy(const float* __restrict__ pk,
    const float* __restrict__ pv, float* __restrict__ keys, float* __restrict__ values,
    u16* __restrict__ kbb)
{
  int idx = blockIdx.x * 256 + threadIdx.x;  // 786432 quads
  int d4 = idx & 31;
  int rest = idx >> 5;
  int p = rest % 3072, g = rest / 3072;
  f32x4 kq = *(const f32x4*)(pk + (size_t)idx * 4);
  f32x4 vq = *(const f32x4*)(pv + (size_t)idx * 4);
  size_t off = ((size_t)g * NKV + p) * HD_ + d4 * 4;
  *(f32x4*)(keys + off) = kq;
  *(f32x4*)(values + off) = vq;
  u16x4 kb4;
#pragma unroll
  for (int i = 0; i < 4; i++) kb4[i] = f2bf(kq[i]);
  *(u16x4*)(kbb + off) = kb4;
}

// ---- build vT bf16 [8][128][4096] from prev_v (pos<3072) / qkv v-cols ----
__global__ __launch_bounds__(256) void vtrans(const float* __restrict__ pv,
    const float* __restrict__ qkv, u16* __restrict__ vT)
{
  __shared__ float T[64][68];
  int bid = blockIdx.x;  // 1024 = g(8) * pt(64) * dt(2)
  int dt = bid & 1, pt = (bid >> 1) & 63, g = bid >> 7;
  int t = threadIdx.x;
  int pl = t >> 4, dl4 = (t & 15) << 2;
#pragma unroll
  for (int r = 0; r < 4; r++) {
    int row = r * 16 + pl;
    int pos = pt * 64 + row;
    f32x4 v;
    if (pos < START_POS)
      v = *(const f32x4*)(pv + ((size_t)g * START_POS + pos) * HD_ + dt * 64 + dl4);
    else
      v = *(const f32x4*)(qkv + (size_t)(pos - START_POS) * DQKV + 5120 + g * HD_ + dt * 64 + dl4);
    T[row][dl4] = v[0]; T[row][dl4 + 1] = v[1]; T[row][dl4 + 2] = v[2]; T[row][dl4 + 3] = v[3];
  }
  __syncthreads();
  int dl = t >> 2, p0 = (t & 3) << 4;
  u16x8 lo, hi;
#pragma unroll
  for (int j = 0; j < 8; j++) lo[j] = f2bf(T[p0 + j][dl]);
#pragma unroll
  for (int j = 0; j < 8; j++) hi[j] = f2bf(T[p0 + 8 + j][dl]);
  u16* dst = vT + ((size_t)g * HD_ + dt * 64 + dl) * NKV + pt * 64 + p0;
  *(u16x8*)dst = lo;
  *(u16x8*)(dst + 8) = hi;
}

// ---- flash attention v5e (verified r15): v5d structure + C2 folded into Q ----
__global__ __launch_bounds__(128, 2) void attn_fwd(
    const u16* __restrict__ qb, const u16* __restrict__ kb,
    const u16* __restrict__ vT, float* __restrict__ Opart, float* __restrict__ Ml)
{
  __shared__ u16 Ks[2 * 32 * 128];   // [buf][kv 32][d 128], 16B-slot XOR swizzle
  __shared__ u16 Vs[2 * 128 * 32];   // [buf][d 128][kv 32], slot^((d>>1)&3) swizzle
  int bid = blockIdx.x;
  int g = bid & 7, j = bid >> 3;     // XCD x owns KV group g=x; j in [0,128)
  int sp = j >> 6, jj = j & 63;
  int h = g * 4 + (jj >> 4), qt = jj & 15;
  int tid = threadIdx.x, lane = tid & 63, w = tid >> 6;
  int c32 = lane & 31, h8 = lane >> 5;
  int qw0 = qt * 64 + w * 32;
  bf16x8 Qf[8];
#pragma unroll
  for (int dc = 0; dc < 8; dc++)
    Qf[dc] = *(const bf16x8*)(qb + ((size_t)(h * 1024 + qw0 + c32)) * 128 + dc * 16 + h8 * 8);
  f32x16 O0 = {}, O1 = {}, O2 = {}, O3 = {};
  float Mx = -1e30f, Ls = 0.f;
  // balanced split: sp0 = [0, 49+qt) (provably unmasked), sp1 = [49+qt, 98+2qt)
  int t0 = sp ? (49 + qt) : 0;
  int t1 = sp ? (98 + 2 * qt) : (49 + qt);

#define STAGE_KV(tt, bo) do { \
  _Pragma("unroll") \
  for (int r = 0; r < 4; r++) { \
    int s = w * 256 + r * 64 + lane; \
    int krow = s >> 4, sl = s & 15; \
    gll16(kb + ((size_t)(g * 4096 + (tt) * 32 + krow)) * 128 + (sl ^ (krow & 7)) * 8, \
          Ks + (bo) + (w * 256 + r * 64) * 8); \
    int d = s >> 2, sl2 = s & 3; \
    gll16(vT + ((size_t)(g * 128 + d)) * 4096 + (tt) * 32 + (sl2 ^ ((d >> 1) & 3)) * 8, \
          Vs + (bo) + (w * 256 + r * 64) * 8); \
  } \
} while (0)

  int cur = 0;
  STAGE_KV(t0, 0);
  __syncthreads();
  int vxr = (c32 >> 1) & 3;  // ((32*db + c32)>>1)&3 == (c32>>1)&3 for all db
  for (int t = t0; t < t1; t++) {
    if (t + 1 < t1) STAGE_KV(t + 1, (cur ^ 1) * 4096);
    const u16* Kb = Ks + cur * 4096;
    const u16* Vb = Vs + cur * 4096;
    // S^T = K Q^T : two independent accumulator chains
    f32x16 S0 = {}, Sb = {};
    __builtin_amdgcn_s_setprio(1);
#pragma unroll
    for (int dc = 0; dc < 8; dc += 2) {
      int sxA = (2 * dc + h8) ^ (c32 & 7);
      int sxB = (2 * dc + 2 + h8) ^ (c32 & 7);
      bf16x8 kA = *(const bf16x8*)(Kb + (size_t)c32 * 128 + sxA * 8);
      bf16x8 kB = *(const bf16x8*)(Kb + (size_t)c32 * 128 + sxB * 8);
      S0 = mfma32(kA, Qf[dc], S0);
      Sb = mfma32(kB, Qf[dc + 1], Sb);
    }
    __builtin_amdgcn_s_setprio(0);
#pragma unroll
    for (int r = 0; r < 16; r++) S0[r] += Sb[r];
    // causal mask (only sp=1 blocks near diagonal); S in exp2-domain units
    if (t * 32 + 31 > START_POS + qw0) {
      int qa = START_POS + qw0 + c32;
#pragma unroll
      for (int r = 0; r < 16; r++) {
        int kvo = t * 32 + (r & 3) + 8 * (r >> 2) + 4 * h8;
        if (kvo > qa) S0[r] = -1e30f;
      }
    }
    // row max: 15-op tree + cross-half via shfl_xor(32)
    float tm[16];
#pragma unroll
    for (int r = 0; r < 16; r++) tm[r] = S0[r];
#pragma unroll
    for (int sft = 8; sft >= 1; sft >>= 1)
#pragma unroll
      for (int r = 0; r < sft; r++) tm[r] = fmaxf(tm[r], tm[r + sft]);
    float full = fmaxf(tm[0], __shfl_xor(tm[0], 32));
    // defer-max (T13), exp2-domain threshold 8
    if (!__all(full <= Mx + 8.0f)) {
      float Mn = fmaxf(Mx, full);
      float al = exp2f(Mx - Mn);
      Mx = Mn;
      Ls *= al;
#pragma unroll
      for (int r = 0; r < 16; r++) { O0[r] *= al; O1[r] *= al; O2[r] *= al; O3[r] *= al; }
    }
#pragma unroll
    for (int r = 0; r < 16; r++) S0[r] = exp2f(S0[r] - Mx);
    // row sum
    float ts[16];
#pragma unroll
    for (int r = 0; r < 16; r++) ts[r] = S0[r];
#pragma unroll
    for (int sft = 8; sft >= 1; sft >>= 1)
#pragma unroll
      for (int r = 0; r < sft; r++) ts[r] = ts[r] + ts[r + sft];
    Ls += ts[0] + __shfl_xor(ts[0], 32);
    // pack P + cross-half exchange (verified routing)
    u32 pk0[8], x0[8];
#pragma unroll
    for (int m = 0; m < 8; m++) pk0[m] = pack2bf(S0[2 * m], S0[2 * m + 1]);
#pragma unroll
    for (int m = 0; m < 8; m++) x0[m] = __shfl_xor(pk0[m], 32);
    bf16x8 pbf[2];
    {
      u32x4 f0 = { h8 ? x0[2] : pk0[0], h8 ? x0[3] : pk0[1],
                   h8 ? pk0[2] : x0[0], h8 ? pk0[3] : x0[1] };
      u32x4 f1 = { h8 ? x0[6] : pk0[4], h8 ? x0[7] : pk0[5],
                   h8 ? pk0[6] : x0[4], h8 ? pk0[7] : x0[5] };
      pbf[0] = __builtin_bit_cast(bf16x8, f0);
      pbf[1] = __builtin_bit_cast(bf16x8, f1);
    }
    // O^T += V^T P^T
    __builtin_amdgcn_s_setprio(1);
#pragma unroll
    for (int kc = 0; kc < 2; kc++) {
      int sv = 2 * kc + h8;
      int sx = (sv ^ vxr) * 8;
      {
        bf16x8 vf = *(const bf16x8*)(Vb + (size_t)(0 * 32 + c32) * 32 + sx);
        O0 = mfma32(vf, pbf[kc], O0);
      }
      {
        bf16x8 vf = *(const bf16x8*)(Vb + (size_t)(1 * 32 + c32) * 32 + sx);
        O1 = mfma32(vf, pbf[kc], O1);
      }
      {
        bf16x8 vf = *(const bf16x8*)(Vb + (size_t)(2 * 32 + c32) * 32 + sx);
        O2 = mfma32(vf, pbf[kc], O2);
      }
      {
        bf16x8 vf = *(const bf16x8*)(Vb + (size_t)(3 * 32 + c32) * 32 + sx);
        O3 = mfma32(vf, pbf[kc], O3);
      }
    }
    __builtin_amdgcn_s_setprio(0);
    __syncthreads();
    cur ^= 1;
  }
#undef STAGE_KV
  // epilogue: raw partial O (f32) + (Mx, Ls)
  {
    float* Orow = Opart + (size_t)sp * 4194304 + (size_t)(qw0 + c32) * 4096 + h * 128;
#pragma unroll
    for (int a = 0; a < 4; a++) {
      f32x4 o0, o1, o2, o3;
#pragma unroll
      for (int b = 0; b < 4; b++) {
        o0[b] = O0[4 * a + b]; o1[b] = O1[4 * a + b];
        o2[b] = O2[4 * a + b]; o3[b] = O3[4 * a + b];
      }
      int d0 = 8 * a + 4 * h8;
      *(f32x4*)(Orow + d0) = o0;
      *(f32x4*)(Orow + 32 + d0) = o1;
      *(f32x4*)(Orow + 64 + d0) = o2;
      *(f32x4*)(Orow + 96 + d0) = o3;
    }
    if (h8 == 0) {
      float* mp = Ml + ((size_t)(sp * 32 + h) * 1024 + qw0 + c32) * 2;
      mp[0] = Mx; mp[1] = Ls;
    }
  }
}

// ---- combine the two KV-split halves -> ctxb bf16 (exp2-domain m) ----
__global__ __launch_bounds__(256) void attn_combine(const float* __restrict__ Opart,
    const float* __restrict__ Ml, u16* __restrict__ ctxb)
{
  int idx = blockIdx.x * 256 + threadIdx.x;  // 1048576
  int q = idx >> 10, c4 = idx & 1023;
  int col = c4 * 4, h = col >> 7;
  const float* m0p = Ml + ((size_t)h * 1024 + q) * 2;
  const float* m1p = Ml + ((size_t)(32 + h) * 1024 + q) * 2;
  float m0 = m0p[0], l0 = m0p[1];
  float m1 = m1p[0], l1 = m1p[1];
  float M = fmaxf(m0, m1);
  float w0 = exp2f(m0 - M);
  float w1 = exp2f(m1 - M);
  float inv = 1.0f / (l0 * w0 + l1 * w1);
  f32x4 a = *(const f32x4*)(Opart + (size_t)q * 4096 + col);
  f32x4 b = *(const f32x4*)(Opart + 4194304 + (size_t)q * 4096 + col);
  u16x4 o;
#pragma unroll
  for (int i = 0; i < 4; i++) o[i] = f2bf((a[i] * w0 + b[i] * w1) * inv);
  *(u16x4*)(ctxb + (size_t)q * 4096 + col) = o;
}

extern "C" void kernel_launch(void* const* d_in, const int* in_sizes, int n_in,
                              void* d_out, int out_size, void* d_ws, size_t ws_size,
                              hipStream_t stream) {
  const float* x      = (const float*)d_in[0];
  const float* cosb   = (const float*)d_in[2];
  const float* sinb   = (const float*)d_in[3];
  const float* prev_k = (const float*)d_in[5];
  const float* prev_v = (const float*)d_in[6];
  const float* Wq     = (const float*)d_in[7];
  const float* Wk     = (const float*)d_in[8];
  const float* Wv     = (const float*)d_in[9];
  const float* Wo     = (const float*)d_in[10];

  // workspace layout (~144 MB)
  u16* Wt_proj = (u16*)d_ws;                                  // [6144][4096] bf16 (50.3MB)
  u16* Wt_out  = Wt_proj + (size_t)6144 * 4096;               // [4096][4096] bf16
  u16* xb      = Wt_out + (size_t)4096 * 4096;                // [1024][4096] bf16
  float* qkv   = (float*)(xb + (size_t)1024 * 4096);          // [1024][6144] f32
  u16* qb      = (u16*)(qkv + (size_t)1024 * 6144);           // [32][1024][128]
  u16* kbb     = qb + (size_t)32 * 1024 * 128;                // [8][4096][128]
  u16* vT      = kbb + (size_t)8 * 4096 * 128;                // [8][128][4096]
  u16* ctxb    = vT + (size_t)8 * 4096 * 128;                 // [1024][4096]
  // attn partials ALIAS Wt_proj (dead after gemm1; rewritten each call): 32.5MB < 50.3MB
  float* Opart = (float*)d_ws;                                // [2][1024][4096] f32
  float* Ml    = Opart + (size_t)2 * 1024 * 4096;             // [2][32][1024][2] f32

  float* outp   = (float*)d_out;
  float* keys   = outp + (size_t)4194304;
  float* values = outp + (size_t)8388608;

  wtrans<<<4096, 256, 0, stream>>>(Wq, Wt_proj, 4096, 64, 0);
  wtrans<<<1024, 256, 0, stream>>>(Wk, Wt_proj, 1024, 16, 4096);
  wtrans<<<1024, 256, 0, stream>>>(Wv, Wt_proj, 1024, 16, 5120);
  wtrans<<<4096, 256, 0, stream>>>(Wo, Wt_out, 4096, 64, 0);
  cvt_bf16<<<4096, 256, 0, stream>>>(x, xb, 1048576);

  gemm_bt<<<768, 256, 0, stream>>>(xb, Wt_proj, qkv, 6144, 4096, 96);

  rope_q<<<2048, 256, 0, stream>>>(qkv, cosb, sinb, qb);
  rope_k<<<512, 256, 0, stream>>>(qkv, cosb, sinb, keys, kbb);
  copy_vnew<<<1024, 256, 0, stream>>>(qkv, values);
  prev_copy<<<3072, 256, 0, stream>>>(prev_k, prev_v, keys, values, kbb);
  vtrans<<<1024, 256, 0, stream>>>(prev_v, qkv, vT);

  attn_fwd<<<1024, 128, 0, stream>>>(qb, kbb, vT, Opart, Ml);
  attn_combine<<<4096, 256, 0, stream>>>(Opart, Ml, ctxb);

  gemm_bt<<<512, 256, 0, stream>>>(ctxb, Wt_out, outp, 4096, 4096, 64);
}

// Round 17
// 345.688 us; speedup vs baseline: 1.1523x; 1.0002x over previous
//
#include <hip/hip_runtime.h>
#include <hip/hip_bf16.h>

typedef unsigned short u16;
typedef unsigned int u32;
typedef __attribute__((ext_vector_type(4))) float f32x4;
typedef __attribute__((ext_vector_type(16))) float f32x16;
typedef __attribute__((ext_vector_type(8))) __bf16 bf16x8;
typedef __attribute__((ext_vector_type(4))) u16 u16x4;
typedef __attribute__((ext_vector_type(8))) u16 u16x8;
typedef __attribute__((ext_vector_type(4))) u32 u32x4;

#define START_POS 3072
#define NKV 4096
#define HD_ 128
#define SEQ 1024
#define DIN_ 4096
#define DQKV 6144

__device__ __forceinline__ void gll16(const void* g, void* l) {
  __builtin_amdgcn_global_load_lds((const __attribute__((address_space(1))) u32*)g,
                                   (__attribute__((address_space(3))) u32*)l, 16, 0, 0);
}
__device__ __forceinline__ u16 f2bf(float f) {
  u32 u = __builtin_bit_cast(u32, f);
  return (u16)((u + 0x7fffu + ((u >> 16) & 1u)) >> 16);
}
__device__ __forceinline__ u32 pack2bf(float a, float b) {
  __hip_bfloat162 t = __float22bfloat162_rn(float2{a, b});  // low=a, high=b, RNE
  u32 u; __builtin_memcpy(&u, &t, 4);
  return u;
}
__device__ __forceinline__ f32x4 mfma16(bf16x8 a, bf16x8 b, f32x4 c) {
  return __builtin_amdgcn_mfma_f32_16x16x32_bf16(a, b, c, 0, 0, 0);
}
__device__ __forceinline__ f32x16 mfma32(bf16x8 a, bf16x8 b, f32x16 c) {
  return __builtin_amdgcn_mfma_f32_32x32x16_bf16(a, b, c, 0, 0, 0);
}

// ---- transpose+convert W f32 [K=4096][N] -> Wt bf16 [N][4096] ----
__global__ __launch_bounds__(256) void wtrans(const float* __restrict__ W,
    u16* __restrict__ Wt, int N, int ntn, int row_off)
{
  __shared__ float T[64][68];
  int bid = blockIdx.x;
  int nt = bid % ntn, kt = bid / ntn;
  int t = threadIdx.x;
  int kl = t >> 4, nl4 = (t & 15) << 2;
#pragma unroll
  for (int r = 0; r < 4; r++) {
    int row = r * 16 + kl;
    f32x4 v = *(const f32x4*)(W + (size_t)(kt * 64 + row) * N + nt * 64 + nl4);
    T[row][nl4] = v[0]; T[row][nl4 + 1] = v[1]; T[row][nl4 + 2] = v[2]; T[row][nl4 + 3] = v[3];
  }
  __syncthreads();
  int nl = t >> 2, k0 = (t & 3) << 4;
  u16x8 lo, hi;
#pragma unroll
  for (int j = 0; j < 8; j++) lo[j] = f2bf(T[k0 + j][nl]);
#pragma unroll
  for (int j = 0; j < 8; j++) hi[j] = f2bf(T[k0 + 8 + j][nl]);
  u16* dst = Wt + (size_t)(row_off + nt * 64 + nl) * 4096 + kt * 64 + k0;
  *(u16x8*)dst = lo;
  *(u16x8*)(dst + 8) = hi;
}

// ---- f32 -> bf16 convert ----
__global__ __launch_bounds__(256) void cvt_bf16(const float* __restrict__ src,
    u16* __restrict__ dst, int n4)
{
  int i = blockIdx.x * 256 + threadIdx.x;
  if (i >= n4) return;
  f32x4 v = *(const f32x4*)(src + (size_t)i * 4);
  u16x4 o;
#pragma unroll
  for (int j = 0; j < 4; j++) o[j] = f2bf(v[j]);
  *(u16x4*)(dst + (size_t)i * 4) = o;
}

// ---- bf16 GEMM v4: 128x64 tile, BK=64, dbuf 2-phase, T2 swizzle (8-slot rows) ----
__global__ __launch_bounds__(256) void gemm_bt(
    const u16* __restrict__ A, const u16* __restrict__ Bt,
    float* __restrict__ C, int N, int K, int nbx)
{
  __shared__ u16 As[2 * 128 * 64];   // 32KB
  __shared__ u16 Bs[2 * 64 * 64];    // 16KB
  int nwg = (int)gridDim.x;
  int orig = blockIdx.x;
  int q8 = nwg >> 3, r8 = nwg & 7;
  int xcd = orig & 7, jj = orig >> 3;
  int wgid = (xcd < r8 ? xcd * (q8 + 1) : r8 * (q8 + 1) + (xcd - r8) * q8) + jj;
  int by = wgid / nbx, bx = wgid % nbx;
  int tid = threadIdx.x, lane = tid & 63, wid = tid >> 6;
  int wr = wid >> 1, wc = wid & 1;
  int c = lane & 15, hh = lane >> 4;
  int srow = lane >> 3;
  int schunk = ((lane & 7) ^ srow) << 3;
  const u16* aS0 = A + (size_t)(by * 128 + wid * 32 + srow) * K + schunk;
  const u16* bS0 = Bt + (size_t)(bx * 64 + wid * 16 + srow) * K + schunk;

#define GSTAGE(buf, kk) do { \
  _Pragma("unroll") \
  for (int r = 0; r < 4; r++) \
    gll16(aS0 + (size_t)r * 8 * K + (kk), As + (buf) * 8192 + (wid * 32 + r * 8) * 64); \
  _Pragma("unroll") \
  for (int r = 0; r < 2; r++) \
    gll16(bS0 + (size_t)r * 8 * K + (kk), Bs + (buf) * 4096 + (wid * 16 + r * 8) * 64); \
} while (0)

  f32x4 acc[4][2] = {};
  int nk = K >> 6;
  int cur = 0;
  int rsl = c & 7;
  GSTAGE(0, 0);
  __syncthreads();
  for (int kt = 0; kt < nk; kt++) {
    if (kt + 1 < nk) GSTAGE(cur ^ 1, (kt + 1) * 64);
    const u16* Ab = As + cur * 8192;
    const u16* Bb = Bs + cur * 4096;
#pragma unroll
    for (int kk = 0; kk < 2; kk++) {
      int slot = ((kk * 4 + hh) ^ rsl) * 8;
      bf16x8 af[4], bf[2];
#pragma unroll
      for (int i = 0; i < 4; i++)
        af[i] = *(const bf16x8*)(Ab + (wr * 64 + i * 16 + c) * 64 + slot);
#pragma unroll
      for (int i = 0; i < 2; i++)
        bf[i] = *(const bf16x8*)(Bb + (wc * 32 + i * 16 + c) * 64 + slot);
      __builtin_amdgcn_s_setprio(1);
#pragma unroll
      for (int mi = 0; mi < 4; mi++)
#pragma unroll
        for (int ni = 0; ni < 2; ni++)
          acc[mi][ni] = mfma16(af[mi], bf[ni], acc[mi][ni]);
      __builtin_amdgcn_s_setprio(0);
    }
    __syncthreads();
    cur ^= 1;
  }
#undef GSTAGE
  int row0 = by * 128 + wr * 64 + hh * 4;
  int col0 = bx * 64 + wc * 32 + c;
#pragma unroll
  for (int mi = 0; mi < 4; mi++)
#pragma unroll
    for (int ni = 0; ni < 2; ni++)
#pragma unroll
      for (int i = 0; i < 4; i++)
        C[(size_t)(row0 + mi * 16 + i) * N + col0 + ni * 16] = acc[mi][ni][i];
}

// ---- RoPE on q part of qkv -> qb bf16 [32][1024][128], PRE-SCALED by log2(e)/sqrt(128) ----
__global__ __launch_bounds__(256) void rope_q(const float* __restrict__ qkv,
    const float* __restrict__ cosb, const float* __restrict__ sinb, u16* __restrict__ qb)
{
  const float C2 = 0.12751744f;
  int tid = blockIdx.x * 256 + threadIdx.x;  // 524288
  int dq = tid & 15, h = (tid >> 4) & 31, s = tid >> 9;
  int d = dq << 2;
  const float* base = qkv + (size_t)s * DQKV + h * HD_ + d;
  f32x4 a = *(const f32x4*)base;
  f32x4 b2 = *(const f32x4*)(base + 64);
  f32x4 cc = *(const f32x4*)(cosb + (size_t)(START_POS + s) * HD_ + d);
  f32x4 sn = *(const f32x4*)(sinb + (size_t)(START_POS + s) * HD_ + d);
  u16x4 o1, o2;
#pragma unroll
  for (int i = 0; i < 4; i++) {
    o1[i] = f2bf((a[i] * cc[i] - b2[i] * sn[i]) * C2);
    o2[i] = f2bf((b2[i] * cc[i] + a[i] * sn[i]) * C2);
  }
  u16* dst = qb + ((size_t)h * SEQ + s) * HD_ + d;
  *(u16x4*)dst = o1;
  *(u16x4*)(dst + 64) = o2;
}

// ---- RoPE on k part -> keys f32 output (pos>=3072) + kb bf16 ----
__global__ __launch_bounds__(256) void rope_k(const float* __restrict__ qkv,
    const float* __restrict__ cosb, const float* __restrict__ sinb,
    float* __restrict__ keys, u16* __restrict__ kbb)
{
  int tid = blockIdx.x * 256 + threadIdx.x;  // 131072
  int dq = tid & 15, g = (tid >> 4) & 7, s = tid >> 7;
  int d = dq << 2;
  const float* base = qkv + (size_t)s * DQKV + DIN_ + g * HD_ + d;
  f32x4 a = *(const f32x4*)base;
  f32x4 b2 = *(const f32x4*)(base + 64);
  f32x4 cc = *(const f32x4*)(cosb + (size_t)(START_POS + s) * HD_ + d);
  f32x4 sn = *(const f32x4*)(sinb + (size_t)(START_POS + s) * HD_ + d);
  f32x4 o1, o2;
  u16x4 p1, p2;
#pragma unroll
  for (int i = 0; i < 4; i++) {
    o1[i] = a[i] * cc[i] - b2[i] * sn[i];
    o2[i] = b2[i] * cc[i] + a[i] * sn[i];
    p1[i] = f2bf(o1[i]);
    p2[i] = f2bf(o2[i]);
  }
  size_t off = ((size_t)g * NKV + START_POS + s) * HD_ + d;
  *(f32x4*)(keys + off) = o1;
  *(f32x4*)(keys + off + 64) = o2;
  *(u16x4*)(kbb + off) = p1;
  *(u16x4*)(kbb + off + 64) = p2;
}

// ---- copy v part -> values f32 output (pos>=3072) ----
__global__ __launch_bounds__(256) void copy_vnew(const float* __restrict__ qkv,
    float* __restrict__ values)
{
  int tid = blockIdx.x * 256 + threadIdx.x;  // 262144
  int dq = tid & 31, g = (tid >> 5) & 7, s = tid >> 8;
  int d = dq << 2;
  f32x4 v = *(const f32x4*)(qkv + (size_t)s * DQKV + DIN_ + 1024 + g * HD_ + d);
  *(f32x4*)(values + ((size_t)g * NKV + START_POS + s) * HD_ + d) = v;
}

// ---- copy prev_k/prev_v -> keys/values f32 outputs + kb bf16 ----
__global__ __launch_bounds__(256) void prev_copy(const float* __restrict__ pk,
    const float* __restrict__ pv, float* __restrict__ keys, float* __restrict__ values,
    u16* __restrict__ kbb)
{
  int idx = blockIdx.x * 256 + threadIdx.x;  // 786432 quads
  int d4 = idx & 31;
  int rest = idx >> 5;
  int p = rest % 3072, g = rest / 3072;
  f32x4 kq = *(const f32x4*)(pk + (size_t)idx * 4);
  f32x4 vq = *(const f32x4*)(pv + (size_t)idx * 4);
  size_t off = ((size_t)g * NKV + p) * HD_ + d4 * 4;
  *(f32x4*)(keys + off) = kq;
  *(f32x4*)(values + off) = vq;
  u16x4 kb4;
#pragma unroll
  for (int i = 0; i < 4; i++) kb4[i] = f2bf(kq[i]);
  *(u16x4*)(kbb + off) = kb4;
}

// ---- build vT bf16 [8][128][4096] from prev_v (pos<3072) / qkv v-cols ----
__global__ __launch_bounds__(256) void vtrans(const float* __restrict__ pv,
    const float* __restrict__ qkv, u16* __restrict__ vT)
{
  __shared__ float T[64][68];
  int bid = blockIdx.x;  // 1024 = g(8) * pt(64) * dt(2)
  int dt = bid & 1, pt = (bid >> 1) & 63, g = bid >> 7;
  int t = threadIdx.x;
  int pl = t >> 4, dl4 = (t & 15) << 2;
#pragma unroll
  for (int r = 0; r < 4; r++) {
    int row = r * 16 + pl;
    int pos = pt * 64 + row;
    f32x4 v;
    if (pos < START_POS)
      v = *(const f32x4*)(pv + ((size_t)g * START_POS + pos) * HD_ + dt * 64 + dl4);
    else
      v = *(const f32x4*)(qkv + (size_t)(pos - START_POS) * DQKV + 5120 + g * HD_ + dt * 64 + dl4);
    T[row][dl4] = v[0]; T[row][dl4 + 1] = v[1]; T[row][dl4 + 2] = v[2]; T[row][dl4 + 3] = v[3];
  }
  __syncthreads();
  int dl = t >> 2, p0 = (t & 3) << 4;
  u16x8 lo, hi;
#pragma unroll
  for (int j = 0; j < 8; j++) lo[j] = f2bf(T[p0 + j][dl]);
#pragma unroll
  for (int j = 0; j < 8; j++) hi[j] = f2bf(T[p0 + 8 + j][dl]);
  u16* dst = vT + ((size_t)g * HD_ + dt * 64 + dl) * NKV + pt * 64 + p0;
  *(u16x8*)dst = lo;
  *(u16x8*)(dst + 8) = hi;
}

// ---- flash attention v8: 4-way KV split, 4-wave blocks (128 q-rows), grid 1024,
// ---- 4 blocks/CU x 4 waves = 16 waves/CU = 4/SIMD. v5e per-tile code unchanged. ----
__global__ __launch_bounds__(256, 2) void attn_fwd(
    const u16* __restrict__ qb, const u16* __restrict__ kb,
    const u16* __restrict__ vT, float* __restrict__ OpA, float* __restrict__ OpB,
    float* __restrict__ Ml)
{
  __shared__ u16 Ks[2 * 32 * 128];   // [buf][kv 32][d 128], 16B-slot XOR swizzle
  __shared__ u16 Vs[2 * 128 * 32];   // [buf][d 128][kv 32], slot^((d>>1)&3) swizzle
  int bid = blockIdx.x;
  int g = bid & 7, j = bid >> 3;     // XCD x owns KV group g=x; j in [0,128)
  int sp = j >> 5, jj = j & 31;      // sp in {0,1,2,3}
  int h = g * 4 + (jj >> 3), qt = jj & 7;
  int tid = threadIdx.x, lane = tid & 63, w = tid >> 6;   // w in [0,4)
  int c32 = lane & 31, h8 = lane >> 5;
  int qw0 = qt * 128 + w * 32;       // this wave's first q row
  bf16x8 Qf[8];
#pragma unroll
  for (int dc = 0; dc < 8; dc++)
    Qf[dc] = *(const bf16x8*)(qb + ((size_t)(h * 1024 + qw0 + c32)) * 128 + dc * 16 + h8 * 8);
  f32x16 O0 = {}, O1 = {}, O2 = {}, O3 = {};
  float Mx = -1e30f, Ls = 0.f;
  // 4-way balanced split of T = 100 + 4*qt tiles; first tile of each sp is unmasked
  int T = 100 + 4 * qt;
  int t0 = (sp * T) >> 2;
  int t1 = ((sp + 1) * T) >> 2;

#define STAGE_KV(tt, bo) do { \
  _Pragma("unroll") \
  for (int r = 0; r < 2; r++) { \
    int s = r * 256 + w * 64 + lane; \
    int krow = s >> 4, sl = s & 15; \
    gll16(kb + ((size_t)(g * 4096 + (tt) * 32 + krow)) * 128 + (sl ^ (krow & 7)) * 8, \
          Ks + (bo) + (r * 256 + w * 64) * 8); \
    int d = s >> 2, sl2 = s & 3; \
    gll16(vT + ((size_t)(g * 128 + d)) * 4096 + (tt) * 32 + (sl2 ^ ((d >> 1) & 3)) * 8, \
          Vs + (bo) + (r * 256 + w * 64) * 8); \
  } \
} while (0)

  int cur = 0;
  STAGE_KV(t0, 0);
  __syncthreads();
  int vxr = (c32 >> 1) & 3;  // ((32*db + c32)>>1)&3 == (c32>>1)&3 for all db
  for (int t = t0; t < t1; t++) {
    if (t + 1 < t1) STAGE_KV(t + 1, (cur ^ 1) * 4096);
    const u16* Kb = Ks + cur * 4096;
    const u16* Vb = Vs + cur * 4096;
    // S^T = K Q^T : two independent accumulator chains
    f32x16 S0 = {}, Sb = {};
    __builtin_amdgcn_s_setprio(1);
#pragma unroll
    for (int dc = 0; dc < 8; dc += 2) {
      int sxA = (2 * dc + h8) ^ (c32 & 7);
      int sxB = (2 * dc + 2 + h8) ^ (c32 & 7);
      bf16x8 kA = *(const bf16x8*)(Kb + (size_t)c32 * 128 + sxA * 8);
      bf16x8 kB = *(const bf16x8*)(Kb + (size_t)c32 * 128 + sxB * 8);
      S0 = mfma32(kA, Qf[dc], S0);
      Sb = mfma32(kB, Qf[dc + 1], Sb);
    }
    __builtin_amdgcn_s_setprio(0);
#pragma unroll
    for (int r = 0; r < 16; r++) S0[r] += Sb[r];
    // causal mask (near-diagonal tiles only); S in exp2-domain units
    if (t * 32 + 31 > START_POS + qw0) {
      int qa = START_POS + qw0 + c32;
#pragma unroll
      for (int r = 0; r < 16; r++) {
        int kvo = t * 32 + (r & 3) + 8 * (r >> 2) + 4 * h8;
        if (kvo > qa) S0[r] = -1e30f;
      }
    }
    // row max: 15-op tree + cross-half via shfl_xor(32)
    float tm[16];
#pragma unroll
    for (int r = 0; r < 16; r++) tm[r] = S0[r];
#pragma unroll
    for (int sft = 8; sft >= 1; sft >>= 1)
#pragma unroll
      for (int r = 0; r < sft; r++) tm[r] = fmaxf(tm[r], tm[r + sft]);
    float full = fmaxf(tm[0], __shfl_xor(tm[0], 32));
    // defer-max (T13), exp2-domain threshold 8
    if (!__all(full <= Mx + 8.0f)) {
      float Mn = fmaxf(Mx, full);
      float al = exp2f(Mx - Mn);
      Mx = Mn;
      Ls *= al;
#pragma unroll
      for (int r = 0; r < 16; r++) { O0[r] *= al; O1[r] *= al; O2[r] *= al; O3[r] *= al; }
    }
#pragma unroll
    for (int r = 0; r < 16; r++) S0[r] = exp2f(S0[r] - Mx);
    // row sum
    float ts[16];
#pragma unroll
    for (int r = 0; r < 16; r++) ts[r] = S0[r];
#pragma unroll
    for (int sft = 8; sft >= 1; sft >>= 1)
#pragma unroll
      for (int r = 0; r < sft; r++) ts[r] = ts[r] + ts[r + sft];
    Ls += ts[0] + __shfl_xor(ts[0], 32);
    // pack P + cross-half exchange (verified routing)
    u32 pk0[8], x0[8];
#pragma unroll
    for (int m = 0; m < 8; m++) pk0[m] = pack2bf(S0[2 * m], S0[2 * m + 1]);
#pragma unroll
    for (int m = 0; m < 8; m++) x0[m] = __shfl_xor(pk0[m], 32);
    bf16x8 pbf[2];
    {
      u32x4 f0 = { h8 ? x0[2] : pk0[0], h8 ? x0[3] : pk0[1],
                   h8 ? pk0[2] : x0[0], h8 ? pk0[3] : x0[1] };
      u32x4 f1 = { h8 ? x0[6] : pk0[4], h8 ? x0[7] : pk0[5],
                   h8 ? pk0[6] : x0[4], h8 ? pk0[7] : x0[5] };
      pbf[0] = __builtin_bit_cast(bf16x8, f0);
      pbf[1] = __builtin_bit_cast(bf16x8, f1);
    }
    // O^T += V^T P^T
    __builtin_amdgcn_s_setprio(1);
#pragma unroll
    for (int kc = 0; kc < 2; kc++) {
      int sv = 2 * kc + h8;
      int sx = (sv ^ vxr) * 8;
      {
        bf16x8 vf = *(const bf16x8*)(Vb + (size_t)(0 * 32 + c32) * 32 + sx);
        O0 = mfma32(vf, pbf[kc], O0);
      }
      {
        bf16x8 vf = *(const bf16x8*)(Vb + (size_t)(1 * 32 + c32) * 32 + sx);
        O1 = mfma32(vf, pbf[kc], O1);
      }
      {
        bf16x8 vf = *(const bf16x8*)(Vb + (size_t)(2 * 32 + c32) * 32 + sx);
        O2 = mfma32(vf, pbf[kc], O2);
      }
      {
        bf16x8 vf = *(const bf16x8*)(Vb + (size_t)(3 * 32 + c32) * 32 + sx);
        O3 = mfma32(vf, pbf[kc], O3);
      }
    }
    __builtin_amdgcn_s_setprio(0);
    __syncthreads();
    cur ^= 1;
  }
#undef STAGE_KV
  // epilogue: raw partial O (f32) + (Mx, Ls); sp 0-2 -> OpA, sp 3 -> OpB
  {
    float* Obase = (sp < 3) ? (OpA + (size_t)sp * 4194304) : OpB;
    float* Orow = Obase + (size_t)(qw0 + c32) * 4096 + h * 128;
#pragma unroll
    for (int a = 0; a < 4; a++) {
      f32x4 o0, o1, o2, o3;
#pragma unroll
      for (int b = 0; b < 4; b++) {
        o0[b] = O0[4 * a + b]; o1[b] = O1[4 * a + b];
        o2[b] = O2[4 * a + b]; o3[b] = O3[4 * a + b];
      }
      int d0 = 8 * a + 4 * h8;
      *(f32x4*)(Orow + d0) = o0;
      *(f32x4*)(Orow + 32 + d0) = o1;
      *(f32x4*)(Orow + 64 + d0) = o2;
      *(f32x4*)(Orow + 96 + d0) = o3;
    }
    if (h8 == 0) {
      float* mp = Ml + ((size_t)(sp * 32 + h) * 1024 + qw0 + c32) * 2;
      mp[0] = Mx; mp[1] = Ls;
    }
  }
}

// ---- combine the four KV-split parts -> ctxb bf16 (exp2-domain m) ----
__global__ __launch_bounds__(256) void attn_combine(const float* __restrict__ OpA,
    const float* __restrict__ OpB, const float* __restrict__ Ml, u16* __restrict__ ctxb)
{
  int idx = blockIdx.x * 256 + threadIdx.x;  // 1048576
  int q = idx >> 10, c4 = idx & 1023;
  int col = c4 * 4, h = col >> 7;
  float m[4], l[4];
#pragma unroll
  for (int s = 0; s < 4; s++) {
    const float* mp = Ml + ((size_t)(s * 32 + h) * 1024 + q) * 2;
    m[s] = mp[0]; l[s] = mp[1];
  }
  float M = fmaxf(fmaxf(m[0], m[1]), fmaxf(m[2], m[3]));
  float wgt[4];
  float den = 0.f;
#pragma unroll
  for (int s = 0; s < 4; s++) { wgt[s] = exp2f(m[s] - M); den += l[s] * wgt[s]; }
  float inv = 1.0f / den;
  f32x4 a0 = *(const f32x4*)(OpA + (size_t)q * 4096 + col);
  f32x4 a1 = *(const f32x4*)(OpA + 4194304 + (size_t)q * 4096 + col);
  f32x4 a2 = *(const f32x4*)(OpA + 2 * 4194304 + (size_t)q * 4096 + col);
  f32x4 a3 = *(const f32x4*)(OpB + (size_t)q * 4096 + col);
  u16x4 o;
#pragma unroll
  for (int i = 0; i < 4; i++)
    o[i] = f2bf((a0[i] * wgt[0] + a1[i] * wgt[1] + a2[i] * wgt[2] + a3[i] * wgt[3]) * inv);
  *(u16x4*)(ctxb + (size_t)q * 4096 + col) = o;
}

extern "C" void kernel_launch(void* const* d_in, const int* in_sizes, int n_in,
                              void* d_out, int out_size, void* d_ws, size_t ws_size,
                              hipStream_t stream) {
  const float* x      = (const float*)d_in[0];
  const float* cosb   = (const float*)d_in[2];
  const float* sinb   = (const float*)d_in[3];
  const float* prev_k = (const float*)d_in[5];
  const float* prev_v = (const float*)d_in[6];
  const float* Wq     = (const float*)d_in[7];
  const float* Wk     = (const float*)d_in[8];
  const float* Wv     = (const float*)d_in[9];
  const float* Wo     = (const float*)d_in[10];

  // workspace layout (~144 MB)
  u16* Wt_proj = (u16*)d_ws;                                  // [6144][4096] bf16 (50.3MB)
  u16* Wt_out  = Wt_proj + (size_t)6144 * 4096;               // [4096][4096] bf16
  u16* xb      = Wt_out + (size_t)4096 * 4096;                // [1024][4096] bf16
  float* qkv   = (float*)(xb + (size_t)1024 * 4096);          // [1024][6144] f32 (25.2MB)
  u16* qb      = (u16*)(qkv + (size_t)1024 * 6144);           // [32][1024][128]
  u16* kbb     = qb + (size_t)32 * 1024 * 128;                // [8][4096][128]
  u16* vT      = kbb + (size_t)8 * 4096 * 128;                // [8][128][4096]
  u16* ctxb    = vT + (size_t)8 * 4096 * 128;                 // [1024][4096]
  // attn partials: OpA[3] aliases Wt_proj (48MB <= 50.3, dead after gemm1);
  // OpB[1] + Ml alias qkv (16+1MB <= 25.2, dead after vtrans)
  float* OpA = (float*)d_ws;                                  // [3][1024][4096] f32
  float* OpB = qkv;                                           // [1][1024][4096] f32
  float* Ml  = qkv + (size_t)4194304;                         // [4][32][1024][2] f32

  float* outp   = (float*)d_out;
  float* keys   = outp + (size_t)4194304;
  float* values = outp + (size_t)8388608;

  wtrans<<<4096, 256, 0, stream>>>(Wq, Wt_proj, 4096, 64, 0);
  wtrans<<<1024, 256, 0, stream>>>(Wk, Wt_proj, 1024, 16, 4096);
  wtrans<<<1024, 256, 0, stream>>>(Wv, Wt_proj, 1024, 16, 5120);
  wtrans<<<4096, 256, 0, stream>>>(Wo, Wt_out, 4096, 64, 0);
  cvt_bf16<<<4096, 256, 0, stream>>>(x, xb, 1048576);

  gemm_bt<<<768, 256, 0, stream>>>(xb, Wt_proj, qkv, 6144, 4096, 96);

  rope_q<<<2048, 256, 0, stream>>>(qkv, cosb, sinb, qb);
  rope_k<<<512, 256, 0, stream>>>(qkv, cosb, sinb, keys, kbb);
  copy_vnew<<<1024, 256, 0, stream>>>(qkv, values);
  prev_copy<<<3072, 256, 0, stream>>>(prev_k, prev_v, keys, values, kbb);
  vtrans<<<1024, 256, 0, stream>>>(prev_v, qkv, vT);

  attn_fwd<<<1024, 256, 0, stream>>>(qb, kbb, vT, OpA, OpB, Ml);
  attn_combine<<<4096, 256, 0, stream>>>(OpA, OpB, Ml, ctxb);

  gemm_bt<<<512, 256, 0, stream>>>(ctxb, Wt_out, outp, 4096, 4096, 64);
}

// Round 18
// 342.480 us; speedup vs baseline: 1.1631x; 1.0094x over previous
//
#include <hip/hip_runtime.h>
#include <hip/hip_bf16.h>

typedef unsigned short u16;
typedef unsigned int u32;
typedef __attribute__((ext_vector_type(4))) float f32x4;
typedef __attribute__((ext_vector_type(16))) float f32x16;
typedef __attribute__((ext_vector_type(8))) __bf16 bf16x8;
typedef __attribute__((ext_vector_type(4))) u16 u16x4;
typedef __attribute__((ext_vector_type(8))) u16 u16x8;
typedef __attribute__((ext_vector_type(4))) u32 u32x4;

#define START_POS 3072
#define NKV 4096
#define HD_ 128
#define SEQ 1024
#define DIN_ 4096
#define DQKV 6144

__device__ __forceinline__ void gll16(const void* g, void* l) {
  __builtin_amdgcn_global_load_lds((const __attribute__((address_space(1))) u32*)g,
                                   (__attribute__((address_space(3))) u32*)l, 16, 0, 0);
}
__device__ __forceinline__ u16 f2bf(float f) {
  u32 u = __builtin_bit_cast(u32, f);
  return (u16)((u + 0x7fffu + ((u >> 16) & 1u)) >> 16);
}
__device__ __forceinline__ float bf2f(u16 u) {
  u32 x = (u32)u << 16;
  return __builtin_bit_cast(float, x);
}
__device__ __forceinline__ u32 pack2bf(float a, float b) {
  __hip_bfloat162 t = __float22bfloat162_rn(float2{a, b});  // low=a, high=b, RNE
  u32 u; __builtin_memcpy(&u, &t, 4);
  return u;
}
__device__ __forceinline__ f32x4 mfma16(bf16x8 a, bf16x8 b, f32x4 c) {
  return __builtin_amdgcn_mfma_f32_16x16x32_bf16(a, b, c, 0, 0, 0);
}
__device__ __forceinline__ f32x16 mfma32(bf16x8 a, bf16x8 b, f32x16 c) {
  return __builtin_amdgcn_mfma_f32_32x32x16_bf16(a, b, c, 0, 0, 0);
}

// ---- transpose+convert W f32 [K=4096][N] -> Wt bf16 [N][4096] ----
__global__ __launch_bounds__(256) void wtrans(const float* __restrict__ W,
    u16* __restrict__ Wt, int N, int ntn, int row_off)
{
  __shared__ float T[64][68];
  int bid = blockIdx.x;
  int nt = bid % ntn, kt = bid / ntn;
  int t = threadIdx.x;
  int kl = t >> 4, nl4 = (t & 15) << 2;
#pragma unroll
  for (int r = 0; r < 4; r++) {
    int row = r * 16 + kl;
    f32x4 v = *(const f32x4*)(W + (size_t)(kt * 64 + row) * N + nt * 64 + nl4);
    T[row][nl4] = v[0]; T[row][nl4 + 1] = v[1]; T[row][nl4 + 2] = v[2]; T[row][nl4 + 3] = v[3];
  }
  __syncthreads();
  int nl = t >> 2, k0 = (t & 3) << 4;
  u16x8 lo, hi;
#pragma unroll
  for (int j = 0; j < 8; j++) lo[j] = f2bf(T[k0 + j][nl]);
#pragma unroll
  for (int j = 0; j < 8; j++) hi[j] = f2bf(T[k0 + 8 + j][nl]);
  u16* dst = Wt + (size_t)(row_off + nt * 64 + nl) * 4096 + kt * 64 + k0;
  *(u16x8*)dst = lo;
  *(u16x8*)(dst + 8) = hi;
}

// ---- f32 -> bf16 convert ----
__global__ __launch_bounds__(256) void cvt_bf16(const float* __restrict__ src,
    u16* __restrict__ dst, int n4)
{
  int i = blockIdx.x * 256 + threadIdx.x;
  if (i >= n4) return;
  f32x4 v = *(const f32x4*)(src + (size_t)i * 4);
  u16x4 o;
#pragma unroll
  for (int j = 0; j < 4; j++) o[j] = f2bf(v[j]);
  *(u16x4*)(dst + (size_t)i * 4) = o;
}

// ---- bf16 GEMM v4: 128x64 tile, BK=64, dbuf 2-phase, T2 swizzle (8-slot rows) ----
__global__ __launch_bounds__(256) void gemm_bt(
    const u16* __restrict__ A, const u16* __restrict__ Bt,
    float* __restrict__ C, int N, int K, int nbx)
{
  __shared__ u16 As[2 * 128 * 64];   // 32KB
  __shared__ u16 Bs[2 * 64 * 64];    // 16KB
  int nwg = (int)gridDim.x;
  int orig = blockIdx.x;
  int q8 = nwg >> 3, r8 = nwg & 7;
  int xcd = orig & 7, jj = orig >> 3;
  int wgid = (xcd < r8 ? xcd * (q8 + 1) : r8 * (q8 + 1) + (xcd - r8) * q8) + jj;
  int by = wgid / nbx, bx = wgid % nbx;
  int tid = threadIdx.x, lane = tid & 63, wid = tid >> 6;
  int wr = wid >> 1, wc = wid & 1;
  int c = lane & 15, hh = lane >> 4;
  int srow = lane >> 3;
  int schunk = ((lane & 7) ^ srow) << 3;
  const u16* aS0 = A + (size_t)(by * 128 + wid * 32 + srow) * K + schunk;
  const u16* bS0 = Bt + (size_t)(bx * 64 + wid * 16 + srow) * K + schunk;

#define GSTAGE(buf, kk) do { \
  _Pragma("unroll") \
  for (int r = 0; r < 4; r++) \
    gll16(aS0 + (size_t)r * 8 * K + (kk), As + (buf) * 8192 + (wid * 32 + r * 8) * 64); \
  _Pragma("unroll") \
  for (int r = 0; r < 2; r++) \
    gll16(bS0 + (size_t)r * 8 * K + (kk), Bs + (buf) * 4096 + (wid * 16 + r * 8) * 64); \
} while (0)

  f32x4 acc[4][2] = {};
  int nk = K >> 6;
  int cur = 0;
  int rsl = c & 7;
  GSTAGE(0, 0);
  __syncthreads();
  for (int kt = 0; kt < nk; kt++) {
    if (kt + 1 < nk) GSTAGE(cur ^ 1, (kt + 1) * 64);
    const u16* Ab = As + cur * 8192;
    const u16* Bb = Bs + cur * 4096;
#pragma unroll
    for (int kk = 0; kk < 2; kk++) {
      int slot = ((kk * 4 + hh) ^ rsl) * 8;
      bf16x8 af[4], bf[2];
#pragma unroll
      for (int i = 0; i < 4; i++)
        af[i] = *(const bf16x8*)(Ab + (wr * 64 + i * 16 + c) * 64 + slot);
#pragma unroll
      for (int i = 0; i < 2; i++)
        bf[i] = *(const bf16x8*)(Bb + (wc * 32 + i * 16 + c) * 64 + slot);
      __builtin_amdgcn_s_setprio(1);
#pragma unroll
      for (int mi = 0; mi < 4; mi++)
#pragma unroll
        for (int ni = 0; ni < 2; ni++)
          acc[mi][ni] = mfma16(af[mi], bf[ni], acc[mi][ni]);
      __builtin_amdgcn_s_setprio(0);
    }
    __syncthreads();
    cur ^= 1;
  }
#undef GSTAGE
  int row0 = by * 128 + wr * 64 + hh * 4;
  int col0 = bx * 64 + wc * 32 + c;
#pragma unroll
  for (int mi = 0; mi < 4; mi++)
#pragma unroll
    for (int ni = 0; ni < 2; ni++)
#pragma unroll
      for (int i = 0; i < 4; i++)
        C[(size_t)(row0 + mi * 16 + i) * N + col0 + ni * 16] = acc[mi][ni][i];
}

// ---- RoPE on q part of qkv -> qb bf16 [32][1024][128], PRE-SCALED by log2(e)/sqrt(128) ----
__global__ __launch_bounds__(256) void rope_q(const float* __restrict__ qkv,
    const float* __restrict__ cosb, const float* __restrict__ sinb, u16* __restrict__ qb)
{
  const float C2 = 0.12751744f;
  int tid = blockIdx.x * 256 + threadIdx.x;  // 524288
  int dq = tid & 15, h = (tid >> 4) & 31, s = tid >> 9;
  int d = dq << 2;
  const float* base = qkv + (size_t)s * DQKV + h * HD_ + d;
  f32x4 a = *(const f32x4*)base;
  f32x4 b2 = *(const f32x4*)(base + 64);
  f32x4 cc = *(const f32x4*)(cosb + (size_t)(START_POS + s) * HD_ + d);
  f32x4 sn = *(const f32x4*)(sinb + (size_t)(START_POS + s) * HD_ + d);
  u16x4 o1, o2;
#pragma unroll
  for (int i = 0; i < 4; i++) {
    o1[i] = f2bf((a[i] * cc[i] - b2[i] * sn[i]) * C2);
    o2[i] = f2bf((b2[i] * cc[i] + a[i] * sn[i]) * C2);
  }
  u16* dst = qb + ((size_t)h * SEQ + s) * HD_ + d;
  *(u16x4*)dst = o1;
  *(u16x4*)(dst + 64) = o2;
}

// ---- RoPE on k part -> keys f32 output (pos>=3072) + kb bf16 ----
__global__ __launch_bounds__(256) void rope_k(const float* __restrict__ qkv,
    const float* __restrict__ cosb, const float* __restrict__ sinb,
    float* __restrict__ keys, u16* __restrict__ kbb)
{
  int tid = blockIdx.x * 256 + threadIdx.x;  // 131072
  int dq = tid & 15, g = (tid >> 4) & 7, s = tid >> 7;
  int d = dq << 2;
  const float* base = qkv + (size_t)s * DQKV + DIN_ + g * HD_ + d;
  f32x4 a = *(const f32x4*)base;
  f32x4 b2 = *(const f32x4*)(base + 64);
  f32x4 cc = *(const f32x4*)(cosb + (size_t)(START_POS + s) * HD_ + d);
  f32x4 sn = *(const f32x4*)(sinb + (size_t)(START_POS + s) * HD_ + d);
  f32x4 o1, o2;
  u16x4 p1, p2;
#pragma unroll
  for (int i = 0; i < 4; i++) {
    o1[i] = a[i] * cc[i] - b2[i] * sn[i];
    o2[i] = b2[i] * cc[i] + a[i] * sn[i];
    p1[i] = f2bf(o1[i]);
    p2[i] = f2bf(o2[i]);
  }
  size_t off = ((size_t)g * NKV + START_POS + s) * HD_ + d;
  *(f32x4*)(keys + off) = o1;
  *(f32x4*)(keys + off + 64) = o2;
  *(u16x4*)(kbb + off) = p1;
  *(u16x4*)(kbb + off + 64) = p2;
}

// ---- copy v part -> values f32 output (pos>=3072) ----
__global__ __launch_bounds__(256) void copy_vnew(const float* __restrict__ qkv,
    float* __restrict__ values)
{
  int tid = blockIdx.x * 256 + threadIdx.x;  // 262144
  int dq = tid & 31, g = (tid >> 5) & 7, s = tid >> 8;
  int d = dq << 2;
  f32x4 v = *(const f32x4*)(qkv + (size_t)s * DQKV + DIN_ + 1024 + g * HD_ + d);
  *(f32x4*)(values + ((size_t)g * NKV + START_POS + s) * HD_ + d) = v;
}

// ---- copy prev_k/prev_v -> keys/values f32 outputs + kb bf16 ----
__global__ __launch_bounds__(256) void prev_copy(const float* __restrict__ pk,
    const float* __restrict__ pv, float* __restrict__ keys, float* __restrict__ values,
    u16* __restrict__ kbb)
{
  int idx = blockIdx.x * 256 + threadIdx.x;  // 786432 quads
  int d4 = idx & 31;
  int rest = idx >> 5;
  int p = rest % 3072, g = rest / 3072;
  f32x4 kq = *(const f32x4*)(pk + (size_t)idx * 4);
  f32x4 vq = *(const f32x4*)(pv + (size_t)idx * 4);
  size_t off = ((size_t)g * NKV + p) * HD_ + d4 * 4;
  *(f32x4*)(keys + off) = kq;
  *(f32x4*)(values + off) = vq;
  u16x4 kb4;
#pragma unroll
  for (int i = 0; i < 4; i++) kb4[i] = f2bf(kq[i]);
  *(u16x4*)(kbb + off) = kb4;
}

// ---- build vT bf16 [8][128][4096] from prev_v (pos<3072) / qkv v-cols ----
__global__ __launch_bounds__(256) void vtrans(const float* __restrict__ pv,
    const float* __restrict__ qkv, u16* __restrict__ vT)
{
  __shared__ float T[64][68];
  int bid = blockIdx.x;  // 1024 = g(8) * pt(64) * dt(2)
  int dt = bid & 1, pt = (bid >> 1) & 63, g = bid >> 7;
  int t = threadIdx.x;
  int pl = t >> 4, dl4 = (t & 15) << 2;
#pragma unroll
  for (int r = 0; r < 4; r++) {
    int row = r * 16 + pl;
    int pos = pt * 64 + row;
    f32x4 v;
    if (pos < START_POS)
      v = *(const f32x4*)(pv + ((size_t)g * START_POS + pos) * HD_ + dt * 64 + dl4);
    else
      v = *(const f32x4*)(qkv + (size_t)(pos - START_POS) * DQKV + 5120 + g * HD_ + dt * 64 + dl4);
    T[row][dl4] = v[0]; T[row][dl4 + 1] = v[1]; T[row][dl4 + 2] = v[2]; T[row][dl4 + 3] = v[3];
  }
  __syncthreads();
  int dl = t >> 2, p0 = (t & 3) << 4;
  u16x8 lo, hi;
#pragma unroll
  for (int j = 0; j < 8; j++) lo[j] = f2bf(T[p0 + j][dl]);
#pragma unroll
  for (int j = 0; j < 8; j++) hi[j] = f2bf(T[p0 + 8 + j][dl]);
  u16* dst = vT + ((size_t)g * HD_ + dt * 64 + dl) * NKV + pt * 64 + p0;
  *(u16x8*)dst = lo;
  *(u16x8*)(dst + 8) = hi;
}

// ---- flash attention v8b: r17 structure, partials stored as bf16 (half traffic) ----
__global__ __launch_bounds__(256, 2) void attn_fwd(
    const u16* __restrict__ qb, const u16* __restrict__ kb,
    const u16* __restrict__ vT, u16* __restrict__ Op, float* __restrict__ Ml)
{
  __shared__ u16 Ks[2 * 32 * 128];   // [buf][kv 32][d 128], 16B-slot XOR swizzle
  __shared__ u16 Vs[2 * 128 * 32];   // [buf][d 128][kv 32], slot^((d>>1)&3) swizzle
  int bid = blockIdx.x;
  int g = bid & 7, j = bid >> 3;     // XCD x owns KV group g=x; j in [0,128)
  int sp = j >> 5, jj = j & 31;      // sp in {0,1,2,3}
  int h = g * 4 + (jj >> 3), qt = jj & 7;
  int tid = threadIdx.x, lane = tid & 63, w = tid >> 6;   // w in [0,4)
  int c32 = lane & 31, h8 = lane >> 5;
  int qw0 = qt * 128 + w * 32;       // this wave's first q row
  bf16x8 Qf[8];
#pragma unroll
  for (int dc = 0; dc < 8; dc++)
    Qf[dc] = *(const bf16x8*)(qb + ((size_t)(h * 1024 + qw0 + c32)) * 128 + dc * 16 + h8 * 8);
  f32x16 O0 = {}, O1 = {}, O2 = {}, O3 = {};
  float Mx = -1e30f, Ls = 0.f;
  // 4-way balanced split of T = 100 + 4*qt tiles; first tile of each sp is unmasked
  int T = 100 + 4 * qt;
  int t0 = (sp * T) >> 2;
  int t1 = ((sp + 1) * T) >> 2;

#define STAGE_KV(tt, bo) do { \
  _Pragma("unroll") \
  for (int r = 0; r < 2; r++) { \
    int s = r * 256 + w * 64 + lane; \
    int krow = s >> 4, sl = s & 15; \
    gll16(kb + ((size_t)(g * 4096 + (tt) * 32 + krow)) * 128 + (sl ^ (krow & 7)) * 8, \
          Ks + (bo) + (r * 256 + w * 64) * 8); \
    int d = s >> 2, sl2 = s & 3; \
    gll16(vT + ((size_t)(g * 128 + d)) * 4096 + (tt) * 32 + (sl2 ^ ((d >> 1) & 3)) * 8, \
          Vs + (bo) + (r * 256 + w * 64) * 8); \
  } \
} while (0)

  int cur = 0;
  STAGE_KV(t0, 0);
  __syncthreads();
  int vxr = (c32 >> 1) & 3;  // ((32*db + c32)>>1)&3 == (c32>>1)&3 for all db
  for (int t = t0; t < t1; t++) {
    if (t + 1 < t1) STAGE_KV(t + 1, (cur ^ 1) * 4096);
    const u16* Kb = Ks + cur * 4096;
    const u16* Vb = Vs + cur * 4096;
    // S^T = K Q^T : two independent accumulator chains
    f32x16 S0 = {}, Sb = {};
    __builtin_amdgcn_s_setprio(1);
#pragma unroll
    for (int dc = 0; dc < 8; dc += 2) {
      int sxA = (2 * dc + h8) ^ (c32 & 7);
      int sxB = (2 * dc + 2 + h8) ^ (c32 & 7);
      bf16x8 kA = *(const bf16x8*)(Kb + (size_t)c32 * 128 + sxA * 8);
      bf16x8 kB = *(const bf16x8*)(Kb + (size_t)c32 * 128 + sxB * 8);
      S0 = mfma32(kA, Qf[dc], S0);
      Sb = mfma32(kB, Qf[dc + 1], Sb);
    }
    __builtin_amdgcn_s_setprio(0);
#pragma unroll
    for (int r = 0; r < 16; r++) S0[r] += Sb[r];
    // causal mask (near-diagonal tiles only); S in exp2-domain units
    if (t * 32 + 31 > START_POS + qw0) {
      int qa = START_POS + qw0 + c32;
#pragma unroll
      for (int r = 0; r < 16; r++) {
        int kvo = t * 32 + (r & 3) + 8 * (r >> 2) + 4 * h8;
        if (kvo > qa) S0[r] = -1e30f;
      }
    }
    // row max: 15-op tree + cross-half via shfl_xor(32)
    float tm[16];
#pragma unroll
    for (int r = 0; r < 16; r++) tm[r] = S0[r];
#pragma unroll
    for (int sft = 8; sft >= 1; sft >>= 1)
#pragma unroll
      for (int r = 0; r < sft; r++) tm[r] = fmaxf(tm[r], tm[r + sft]);
    float full = fmaxf(tm[0], __shfl_xor(tm[0], 32));
    // defer-max (T13), exp2-domain threshold 8
    if (!__all(full <= Mx + 8.0f)) {
      float Mn = fmaxf(Mx, full);
      float al = exp2f(Mx - Mn);
      Mx = Mn;
      Ls *= al;
#pragma unroll
      for (int r = 0; r < 16; r++) { O0[r] *= al; O1[r] *= al; O2[r] *= al; O3[r] *= al; }
    }
#pragma unroll
    for (int r = 0; r < 16; r++) S0[r] = exp2f(S0[r] - Mx);
    // row sum
    float ts[16];
#pragma unroll
    for (int r = 0; r < 16; r++) ts[r] = S0[r];
#pragma unroll
    for (int sft = 8; sft >= 1; sft >>= 1)
#pragma unroll
      for (int r = 0; r < sft; r++) ts[r] = ts[r] + ts[r + sft];
    Ls += ts[0] + __shfl_xor(ts[0], 32);
    // pack P + cross-half exchange (verified routing)
    u32 pk0[8], x0[8];
#pragma unroll
    for (int m = 0; m < 8; m++) pk0[m] = pack2bf(S0[2 * m], S0[2 * m + 1]);
#pragma unroll
    for (int m = 0; m < 8; m++) x0[m] = __shfl_xor(pk0[m], 32);
    bf16x8 pbf[2];
    {
      u32x4 f0 = { h8 ? x0[2] : pk0[0], h8 ? x0[3] : pk0[1],
                   h8 ? pk0[2] : x0[0], h8 ? pk0[3] : x0[1] };
      u32x4 f1 = { h8 ? x0[6] : pk0[4], h8 ? x0[7] : pk0[5],
                   h8 ? pk0[6] : x0[4], h8 ? pk0[7] : x0[5] };
      pbf[0] = __builtin_bit_cast(bf16x8, f0);
      pbf[1] = __builtin_bit_cast(bf16x8, f1);
    }
    // O^T += V^T P^T
    __builtin_amdgcn_s_setprio(1);
#pragma unroll
    for (int kc = 0; kc < 2; kc++) {
      int sv = 2 * kc + h8;
      int sx = (sv ^ vxr) * 8;
      {
        bf16x8 vf = *(const bf16x8*)(Vb + (size_t)(0 * 32 + c32) * 32 + sx);
        O0 = mfma32(vf, pbf[kc], O0);
      }
      {
        bf16x8 vf = *(const bf16x8*)(Vb + (size_t)(1 * 32 + c32) * 32 + sx);
        O1 = mfma32(vf, pbf[kc], O1);
      }
      {
        bf16x8 vf = *(const bf16x8*)(Vb + (size_t)(2 * 32 + c32) * 32 + sx);
        O2 = mfma32(vf, pbf[kc], O2);
      }
      {
        bf16x8 vf = *(const bf16x8*)(Vb + (size_t)(3 * 32 + c32) * 32 + sx);
        O3 = mfma32(vf, pbf[kc], O3);
      }
    }
    __builtin_amdgcn_s_setprio(0);
    __syncthreads();
    cur ^= 1;
  }
#undef STAGE_KV
  // epilogue: partial O as bf16 + (Mx, Ls) f32
  {
    u16* Orow = Op + (size_t)sp * 4194304 + (size_t)(qw0 + c32) * 4096 + h * 128;
#pragma unroll
    for (int a = 0; a < 4; a++) {
      u16x4 o0, o1, o2, o3;
#pragma unroll
      for (int b = 0; b < 4; b++) {
        o0[b] = f2bf(O0[4 * a + b]); o1[b] = f2bf(O1[4 * a + b]);
        o2[b] = f2bf(O2[4 * a + b]); o3[b] = f2bf(O3[4 * a + b]);
      }
      int d0 = 8 * a + 4 * h8;
      *(u16x4*)(Orow + d0) = o0;
      *(u16x4*)(Orow + 32 + d0) = o1;
      *(u16x4*)(Orow + 64 + d0) = o2;
      *(u16x4*)(Orow + 96 + d0) = o3;
    }
    if (h8 == 0) {
      float* mp = Ml + ((size_t)(sp * 32 + h) * 1024 + qw0 + c32) * 2;
      mp[0] = Mx; mp[1] = Ls;
    }
  }
}

// ---- combine the four KV-split parts (bf16 partials) -> ctxb bf16 ----
__global__ __launch_bounds__(256) void attn_combine(const u16* __restrict__ Op,
    const float* __restrict__ Ml, u16* __restrict__ ctxb)
{
  int idx = blockIdx.x * 256 + threadIdx.x;  // 1048576
  int q = idx >> 10, c4 = idx & 1023;
  int col = c4 * 4, h = col >> 7;
  float m[4], l[4];
#pragma unroll
  for (int s = 0; s < 4; s++) {
    const float* mp = Ml + ((size_t)(s * 32 + h) * 1024 + q) * 2;
    m[s] = mp[0]; l[s] = mp[1];
  }
  float M = fmaxf(fmaxf(m[0], m[1]), fmaxf(m[2], m[3]));
  float wgt[4];
  float den = 0.f;
#pragma unroll
  for (int s = 0; s < 4; s++) { wgt[s] = exp2f(m[s] - M); den += l[s] * wgt[s]; }
  float inv = 1.0f / den;
  float acc[4] = {0.f, 0.f, 0.f, 0.f};
#pragma unroll
  for (int s = 0; s < 4; s++) {
    u16x4 raw = *(const u16x4*)(Op + (size_t)s * 4194304 + (size_t)q * 4096 + col);
#pragma unroll
    for (int i = 0; i < 4; i++) acc[i] += bf2f(raw[i]) * wgt[s];
  }
  u16x4 o;
#pragma unroll
  for (int i = 0; i < 4; i++) o[i] = f2bf(acc[i] * inv);
  *(u16x4*)(ctxb + (size_t)q * 4096 + col) = o;
}

extern "C" void kernel_launch(void* const* d_in, const int* in_sizes, int n_in,
                              void* d_out, int out_size, void* d_ws, size_t ws_size,
                              hipStream_t stream) {
  const float* x      = (const float*)d_in[0];
  const float* cosb   = (const float*)d_in[2];
  const float* sinb   = (const float*)d_in[3];
  const float* prev_k = (const float*)d_in[5];
  const float* prev_v = (const float*)d_in[6];
  const float* Wq     = (const float*)d_in[7];
  const float* Wk     = (const float*)d_in[8];
  const float* Wv     = (const float*)d_in[9];
  const float* Wo     = (const float*)d_in[10];

  // workspace layout (~144 MB)
  u16* Wt_proj = (u16*)d_ws;                                  // [6144][4096] bf16 (50.3MB)
  u16* Wt_out  = Wt_proj + (size_t)6144 * 4096;               // [4096][4096] bf16
  u16* xb      = Wt_out + (size_t)4096 * 4096;                // [1024][4096] bf16
  float* qkv   = (float*)(xb + (size_t)1024 * 4096);          // [1024][6144] f32 (25.2MB)
  u16* qb      = (u16*)(qkv + (size_t)1024 * 6144);           // [32][1024][128]
  u16* kbb     = qb + (size_t)32 * 1024 * 128;                // [8][4096][128]
  u16* vT      = kbb + (size_t)8 * 4096 * 128;                // [8][128][4096]
  u16* ctxb    = vT + (size_t)8 * 4096 * 128;                 // [1024][4096]
  // attn partials: Op[4] bf16 (33.6MB) aliases Wt_proj (50.3MB, dead after gemm1);
  // Ml aliases qkv (dead after vtrans)
  u16* Op   = (u16*)d_ws;                                     // [4][1024][4096] bf16
  float* Ml = qkv;                                            // [4][32][1024][2] f32

  float* outp   = (float*)d_out;
  float* keys   = outp + (size_t)4194304;
  float* values = outp + (size_t)8388608;

  wtrans<<<4096, 256, 0, stream>>>(Wq, Wt_proj, 4096, 64, 0);
  wtrans<<<1024, 256, 0, stream>>>(Wk, Wt_proj, 1024, 16, 4096);
  wtrans<<<1024, 256, 0, stream>>>(Wv, Wt_proj, 1024, 16, 5120);
  wtrans<<<4096, 256, 0, stream>>>(Wo, Wt_out, 4096, 64, 0);
  cvt_bf16<<<4096, 256, 0, stream>>>(x, xb, 1048576);

  gemm_bt<<<768, 256, 0, stream>>>(xb, Wt_proj, qkv, 6144, 4096, 96);

  rope_q<<<2048, 256, 0, stream>>>(qkv, cosb, sinb, qb);
  rope_k<<<512, 256, 0, stream>>>(qkv, cosb, sinb, keys, kbb);
  copy_vnew<<<1024, 256, 0, stream>>>(qkv, values);
  prev_copy<<<3072, 256, 0, stream>>>(prev_k, prev_v, keys, values, kbb);
  vtrans<<<1024, 256, 0, stream>>>(prev_v, qkv, vT);

  attn_fwd<<<1024, 256, 0, stream>>>(qb, kbb, vT, Op, Ml);
  attn_combine<<<4096, 256, 0, stream>>>(Op, Ml, ctxb);

  gemm_bt<<<512, 256, 0, stream>>>(ctxb, Wt_out, outp, 4096, 4096, 64);
}

// Round 19
// 334.279 us; speedup vs baseline: 1.1917x; 1.0245x over previous
//
#include <hip/hip_runtime.h>
#include <hip/hip_bf16.h>

typedef unsigned short u16;
typedef unsigned int u32;
typedef __attribute__((ext_vector_type(4))) float f32x4;
typedef __attribute__((ext_vector_type(16))) float f32x16;
typedef __attribute__((ext_vector_type(8))) __bf16 bf16x8;
typedef __attribute__((ext_vector_type(4))) u16 u16x4;
typedef __attribute__((ext_vector_type(8))) u16 u16x8;
typedef __attribute__((ext_vector_type(4))) u32 u32x4;

#define START_POS 3072
#define NKV 4096
#define HD_ 128
#define SEQ 1024
#define DIN_ 4096
#define DQKV 6144

__device__ __forceinline__ void gll16(const void* g, void* l) {
  __builtin_amdgcn_global_load_lds((const __attribute__((address_space(1))) u32*)g,
                                   (__attribute__((address_space(3))) u32*)l, 16, 0, 0);
}
__device__ __forceinline__ u16 f2bf(float f) {
  u32 u = __builtin_bit_cast(u32, f);
  return (u16)((u + 0x7fffu + ((u >> 16) & 1u)) >> 16);
}
__device__ __forceinline__ float bf2f(u16 u) {
  u32 x = (u32)u << 16;
  return __builtin_bit_cast(float, x);
}
__device__ __forceinline__ u32 pack2bf(float a, float b) {
  __hip_bfloat162 t = __float22bfloat162_rn(float2{a, b});  // low=a, high=b, RNE
  u32 u; __builtin_memcpy(&u, &t, 4);
  return u;
}
__device__ __forceinline__ f32x4 mfma16(bf16x8 a, bf16x8 b, f32x4 c) {
  return __builtin_amdgcn_mfma_f32_16x16x32_bf16(a, b, c, 0, 0, 0);
}
__device__ __forceinline__ f32x16 mfma32(bf16x8 a, bf16x8 b, f32x16 c) {
  return __builtin_amdgcn_mfma_f32_32x32x16_bf16(a, b, c, 0, 0, 0);
}

// ---- transpose+convert W f32 [K=4096][N] -> Wt bf16 [N][4096] ----
__global__ __launch_bounds__(256) void wtrans(const float* __restrict__ W,
    u16* __restrict__ Wt, int N, int ntn, int row_off)
{
  __shared__ float T[64][68];
  int bid = blockIdx.x;
  int nt = bid % ntn, kt = bid / ntn;
  int t = threadIdx.x;
  int kl = t >> 4, nl4 = (t & 15) << 2;
#pragma unroll
  for (int r = 0; r < 4; r++) {
    int row = r * 16 + kl;
    f32x4 v = *(const f32x4*)(W + (size_t)(kt * 64 + row) * N + nt * 64 + nl4);
    T[row][nl4] = v[0]; T[row][nl4 + 1] = v[1]; T[row][nl4 + 2] = v[2]; T[row][nl4 + 3] = v[3];
  }
  __syncthreads();
  int nl = t >> 2, k0 = (t & 3) << 4;
  u16x8 lo, hi;
#pragma unroll
  for (int j = 0; j < 8; j++) lo[j] = f2bf(T[k0 + j][nl]);
#pragma unroll
  for (int j = 0; j < 8; j++) hi[j] = f2bf(T[k0 + 8 + j][nl]);
  u16* dst = Wt + (size_t)(row_off + nt * 64 + nl) * 4096 + kt * 64 + k0;
  *(u16x8*)dst = lo;
  *(u16x8*)(dst + 8) = hi;
}

// ---- f32 -> bf16 convert ----
__global__ __launch_bounds__(256) void cvt_bf16(const float* __restrict__ src,
    u16* __restrict__ dst, int n4)
{
  int i = blockIdx.x * 256 + threadIdx.x;
  if (i >= n4) return;
  f32x4 v = *(const f32x4*)(src + (size_t)i * 4);
  u16x4 o;
#pragma unroll
  for (int j = 0; j < 4; j++) o[j] = f2bf(v[j]);
  *(u16x4*)(dst + (size_t)i * 4) = o;
}

// ---- bf16 GEMM v4: 128x64 tile, BK=64, dbuf 2-phase, T2 swizzle (8-slot rows) ----
__global__ __launch_bounds__(256) void gemm_bt(
    const u16* __restrict__ A, const u16* __restrict__ Bt,
    float* __restrict__ C, int N, int K, int nbx)
{
  __shared__ u16 As[2 * 128 * 64];   // 32KB
  __shared__ u16 Bs[2 * 64 * 64];    // 16KB
  int nwg = (int)gridDim.x;
  int orig = blockIdx.x;
  int q8 = nwg >> 3, r8 = nwg & 7;
  int xcd = orig & 7, jj = orig >> 3;
  int wgid = (xcd < r8 ? xcd * (q8 + 1) : r8 * (q8 + 1) + (xcd - r8) * q8) + jj;
  int by = wgid / nbx, bx = wgid % nbx;
  int tid = threadIdx.x, lane = tid & 63, wid = tid >> 6;
  int wr = wid >> 1, wc = wid & 1;
  int c = lane & 15, hh = lane >> 4;
  int srow = lane >> 3;
  int schunk = ((lane & 7) ^ srow) << 3;
  const u16* aS0 = A + (size_t)(by * 128 + wid * 32 + srow) * K + schunk;
  const u16* bS0 = Bt + (size_t)(bx * 64 + wid * 16 + srow) * K + schunk;

#define GSTAGE(buf, kk) do { \
  _Pragma("unroll") \
  for (int r = 0; r < 4; r++) \
    gll16(aS0 + (size_t)r * 8 * K + (kk), As + (buf) * 8192 + (wid * 32 + r * 8) * 64); \
  _Pragma("unroll") \
  for (int r = 0; r < 2; r++) \
    gll16(bS0 + (size_t)r * 8 * K + (kk), Bs + (buf) * 4096 + (wid * 16 + r * 8) * 64); \
} while (0)

  f32x4 acc[4][2] = {};
  int nk = K >> 6;
  int cur = 0;
  int rsl = c & 7;
  GSTAGE(0, 0);
  __syncthreads();
  for (int kt = 0; kt < nk; kt++) {
    if (kt + 1 < nk) GSTAGE(cur ^ 1, (kt + 1) * 64);
    const u16* Ab = As + cur * 8192;
    const u16* Bb = Bs + cur * 4096;
#pragma unroll
    for (int kk = 0; kk < 2; kk++) {
      int slot = ((kk * 4 + hh) ^ rsl) * 8;
      bf16x8 af[4], bf[2];
#pragma unroll
      for (int i = 0; i < 4; i++)
        af[i] = *(const bf16x8*)(Ab + (wr * 64 + i * 16 + c) * 64 + slot);
#pragma unroll
      for (int i = 0; i < 2; i++)
        bf[i] = *(const bf16x8*)(Bb + (wc * 32 + i * 16 + c) * 64 + slot);
      __builtin_amdgcn_s_setprio(1);
#pragma unroll
      for (int mi = 0; mi < 4; mi++)
#pragma unroll
        for (int ni = 0; ni < 2; ni++)
          acc[mi][ni] = mfma16(af[mi], bf[ni], acc[mi][ni]);
      __builtin_amdgcn_s_setprio(0);
    }
    __syncthreads();
    cur ^= 1;
  }
#undef GSTAGE
  int row0 = by * 128 + wr * 64 + hh * 4;
  int col0 = bx * 64 + wc * 32 + c;
#pragma unroll
  for (int mi = 0; mi < 4; mi++)
#pragma unroll
    for (int ni = 0; ni < 2; ni++)
#pragma unroll
      for (int i = 0; i < 4; i++)
        C[(size_t)(row0 + mi * 16 + i) * N + col0 + ni * 16] = acc[mi][ni][i];
}

// ---- RoPE on q part of qkv -> qb bf16 [32][1024][128], PRE-SCALED by log2(e)/sqrt(128) ----
__global__ __launch_bounds__(256) void rope_q(const float* __restrict__ qkv,
    const float* __restrict__ cosb, const float* __restrict__ sinb, u16* __restrict__ qb)
{
  const float C2 = 0.12751744f;
  int tid = blockIdx.x * 256 + threadIdx.x;  // 524288
  int dq = tid & 15, h = (tid >> 4) & 31, s = tid >> 9;
  int d = dq << 2;
  const float* base = qkv + (size_t)s * DQKV + h * HD_ + d;
  f32x4 a = *(const f32x4*)base;
  f32x4 b2 = *(const f32x4*)(base + 64);
  f32x4 cc = *(const f32x4*)(cosb + (size_t)(START_POS + s) * HD_ + d);
  f32x4 sn = *(const f32x4*)(sinb + (size_t)(START_POS + s) * HD_ + d);
  u16x4 o1, o2;
#pragma unroll
  for (int i = 0; i < 4; i++) {
    o1[i] = f2bf((a[i] * cc[i] - b2[i] * sn[i]) * C2);
    o2[i] = f2bf((b2[i] * cc[i] + a[i] * sn[i]) * C2);
  }
  u16* dst = qb + ((size_t)h * SEQ + s) * HD_ + d;
  *(u16x4*)dst = o1;
  *(u16x4*)(dst + 64) = o2;
}

// ---- RoPE on k part -> keys f32 output (pos>=3072) + kb bf16 ----
__global__ __launch_bounds__(256) void rope_k(const float* __restrict__ qkv,
    const float* __restrict__ cosb, const float* __restrict__ sinb,
    float* __restrict__ keys, u16* __restrict__ kbb)
{
  int tid = blockIdx.x * 256 + threadIdx.x;  // 131072
  int dq = tid & 15, g = (tid >> 4) & 7, s = tid >> 7;
  int d = dq << 2;
  const float* base = qkv + (size_t)s * DQKV + DIN_ + g * HD_ + d;
  f32x4 a = *(const f32x4*)base;
  f32x4 b2 = *(const f32x4*)(base + 64);
  f32x4 cc = *(const f32x4*)(cosb + (size_t)(START_POS + s) * HD_ + d);
  f32x4 sn = *(const f32x4*)(sinb + (size_t)(START_POS + s) * HD_ + d);
  f32x4 o1, o2;
  u16x4 p1, p2;
#pragma unroll
  for (int i = 0; i < 4; i++) {
    o1[i] = a[i] * cc[i] - b2[i] * sn[i];
    o2[i] = b2[i] * cc[i] + a[i] * sn[i];
    p1[i] = f2bf(o1[i]);
    p2[i] = f2bf(o2[i]);
  }
  size_t off = ((size_t)g * NKV + START_POS + s) * HD_ + d;
  *(f32x4*)(keys + off) = o1;
  *(f32x4*)(keys + off + 64) = o2;
  *(u16x4*)(kbb + off) = p1;
  *(u16x4*)(kbb + off + 64) = p2;
}

// ---- copy v part -> values f32 output (pos>=3072) ----
__global__ __launch_bounds__(256) void copy_vnew(const float* __restrict__ qkv,
    float* __restrict__ values)
{
  int tid = blockIdx.x * 256 + threadIdx.x;  // 262144
  int dq = tid & 31, g = (tid >> 5) & 7, s = tid >> 8;
  int d = dq << 2;
  f32x4 v = *(const f32x4*)(qkv + (size_t)s * DQKV + DIN_ + 1024 + g * HD_ + d);
  *(f32x4*)(values + ((size_t)g * NKV + START_POS + s) * HD_ + d) = v;
}

// ---- copy prev_k/prev_v -> keys/values f32 outputs + kb bf16 ----
__global__ __launch_bounds__(256) void prev_copy(const float* __restrict__ pk,
    const float* __restrict__ pv, float* __restrict__ keys, float* __restrict__ values,
    u16* __restrict__ kbb)
{
  int idx = blockIdx.x * 256 + threadIdx.x;  // 786432 quads
  int d4 = idx & 31;
  int rest = idx >> 5;
  int p = rest % 3072, g = rest / 3072;
  f32x4 kq = *(const f32x4*)(pk + (size_t)idx * 4);
  f32x4 vq = *(const f32x4*)(pv + (size_t)idx * 4);
  size_t off = ((size_t)g * NKV + p) * HD_ + d4 * 4;
  *(f32x4*)(keys + off) = kq;
  *(f32x4*)(values + off) = vq;
  u16x4 kb4;
#pragma unroll
  for (int i = 0; i < 4; i++) kb4[i] = f2bf(kq[i]);
  *(u16x4*)(kbb + off) = kb4;
}

// ---- build vT bf16 [8][128][4096] from prev_v (pos<3072) / qkv v-cols ----
__global__ __launch_bounds__(256) void vtrans(const float* __restrict__ pv,
    const float* __restrict__ qkv, u16* __restrict__ vT)
{
  __shared__ float T[64][68];
  int bid = blockIdx.x;  // 1024 = g(8) * pt(64) * dt(2)
  int dt = bid & 1, pt = (bid >> 1) & 63, g = bid >> 7;
  int t = threadIdx.x;
  int pl = t >> 4, dl4 = (t & 15) << 2;
#pragma unroll
  for (int r = 0; r < 4; r++) {
    int row = r * 16 + pl;
    int pos = pt * 64 + row;
    f32x4 v;
    if (pos < START_POS)
      v = *(const f32x4*)(pv + ((size_t)g * START_POS + pos) * HD_ + dt * 64 + dl4);
    else
      v = *(const f32x4*)(qkv + (size_t)(pos - START_POS) * DQKV + 5120 + g * HD_ + dt * 64 + dl4);
    T[row][dl4] = v[0]; T[row][dl4 + 1] = v[1]; T[row][dl4 + 2] = v[2]; T[row][dl4 + 3] = v[3];
  }
  __syncthreads();
  int dl = t >> 2, p0 = (t & 3) << 4;
  u16x8 lo, hi;
#pragma unroll
  for (int j = 0; j < 8; j++) lo[j] = f2bf(T[p0 + j][dl]);
#pragma unroll
  for (int j = 0; j < 8; j++) hi[j] = f2bf(T[p0 + 8 + j][dl]);
  u16* dst = vT + ((size_t)g * HD_ + dt * 64 + dl) * NKV + pt * 64 + p0;
  *(u16x8*)dst = lo;
  *(u16x8*)(dst + 8) = hi;
}

// ---- flash attention v9: r18 structure + T15 pipeline: PV(t-1) [MFMA] overlaps
// ---- softmax(t) [VALU]. K dbuf (16KB) + V 3-buf (24KB); 1 barrier/tile. ----
__global__ __launch_bounds__(256, 2) void attn_fwd(
    const u16* __restrict__ qb, const u16* __restrict__ kb,
    const u16* __restrict__ vT, u16* __restrict__ Op, float* __restrict__ Ml)
{
  __shared__ u16 Ks[2 * 32 * 128];   // [buf][kv 32][d 128], 16B-slot XOR swizzle
  __shared__ u16 Vs[3 * 128 * 32];   // [buf][d 128][kv 32], slot^((d>>1)&3) swizzle
  int bid = blockIdx.x;
  int g = bid & 7, j = bid >> 3;     // XCD x owns KV group g=x; j in [0,128)
  int sp = j >> 5, jj = j & 31;      // sp in {0,1,2,3}
  int h = g * 4 + (jj >> 3), qt = jj & 7;
  int tid = threadIdx.x, lane = tid & 63, w = tid >> 6;   // w in [0,4)
  int c32 = lane & 31, h8 = lane >> 5;
  int qw0 = qt * 128 + w * 32;       // this wave's first q row
  bf16x8 Qf[8];
#pragma unroll
  for (int dc = 0; dc < 8; dc++)
    Qf[dc] = *(const bf16x8*)(qb + ((size_t)(h * 1024 + qw0 + c32)) * 128 + dc * 16 + h8 * 8);
  f32x16 O0 = {}, O1 = {}, O2 = {}, O3 = {};
  float Mx = -1e30f, Ls = 0.f;
  int T = 100 + 4 * qt;
  int t0 = (sp * T) >> 2;
  int t1 = ((sp + 1) * T) >> 2;      // t1-t0 >= 25; first tile of each sp unmasked

#define STAGE_K(tt, bo) do { \
  _Pragma("unroll") \
  for (int r = 0; r < 2; r++) { \
    int s = r * 256 + w * 64 + lane; \
    int krow = s >> 4, sl = s & 15; \
    gll16(kb + ((size_t)(g * 4096 + (tt) * 32 + krow)) * 128 + (sl ^ (krow & 7)) * 8, \
          Ks + (bo) + (r * 256 + w * 64) * 8); \
  } \
} while (0)
#define STAGE_V(tt, bo) do { \
  _Pragma("unroll") \
  for (int r = 0; r < 2; r++) { \
    int s = r * 256 + w * 64 + lane; \
    int d = s >> 2, sl2 = s & 3; \
    gll16(vT + ((size_t)(g * 128 + d)) * 4096 + (tt) * 32 + (sl2 ^ ((d >> 1) & 3)) * 8, \
          Vs + (bo) + (r * 256 + w * 64) * 8); \
  } \
} while (0)

#define QKT(SS, kbase) do { \
  f32x16 s0_ = {}, sb_ = {}; \
  __builtin_amdgcn_s_setprio(1); \
  _Pragma("unroll") \
  for (int dc = 0; dc < 8; dc += 2) { \
    int sxA_ = (2 * dc + h8) ^ (c32 & 7); \
    int sxB_ = (2 * dc + 2 + h8) ^ (c32 & 7); \
    bf16x8 kA_ = *(const bf16x8*)((kbase) + (size_t)c32 * 128 + sxA_ * 8); \
    bf16x8 kB_ = *(const bf16x8*)((kbase) + (size_t)c32 * 128 + sxB_ * 8); \
    s0_ = mfma32(kA_, Qf[dc], s0_); \
    sb_ = mfma32(kB_, Qf[dc + 1], sb_); \
  } \
  __builtin_amdgcn_s_setprio(0); \
  _Pragma("unroll") \
  for (int r = 0; r < 16; r++) SS[r] = s0_[r] + sb_[r]; \
} while (0)

#define PVACC(PB, vbase) do { \
  __builtin_amdgcn_s_setprio(1); \
  _Pragma("unroll") \
  for (int kc = 0; kc < 2; kc++) { \
    int sx_ = ((2 * kc + h8) ^ vxr) * 8; \
    O0 = mfma32(*(const bf16x8*)((vbase) + (size_t)(0 * 32 + c32) * 32 + sx_), PB[kc], O0); \
    O1 = mfma32(*(const bf16x8*)((vbase) + (size_t)(1 * 32 + c32) * 32 + sx_), PB[kc], O1); \
    O2 = mfma32(*(const bf16x8*)((vbase) + (size_t)(2 * 32 + c32) * 32 + sx_), PB[kc], O2); \
    O3 = mfma32(*(const bf16x8*)((vbase) + (size_t)(3 * 32 + c32) * 32 + sx_), PB[kc], O3); \
  } \
  __builtin_amdgcn_s_setprio(0); \
} while (0)

#define SOFTMAX(tt, SS, NPB) do { \
  if ((tt) * 32 + 31 > START_POS + qw0) { \
    int qa_ = START_POS + qw0 + c32; \
    _Pragma("unroll") \
    for (int r = 0; r < 16; r++) { \
      int kvo_ = (tt) * 32 + (r & 3) + 8 * (r >> 2) + 4 * h8; \
      if (kvo_ > qa_) SS[r] = -1e30f; \
    } \
  } \
  float tm_[16]; \
  _Pragma("unroll") \
  for (int r = 0; r < 16; r++) tm_[r] = SS[r]; \
  _Pragma("unroll") \
  for (int sft = 8; sft >= 1; sft >>= 1) \
    _Pragma("unroll") \
    for (int r = 0; r < sft; r++) tm_[r] = fmaxf(tm_[r], tm_[r + sft]); \
  float full_ = fmaxf(tm_[0], __shfl_xor(tm_[0], 32)); \
  if (!__all(full_ <= Mx + 8.0f)) { \
    float Mn_ = fmaxf(Mx, full_); \
    float al_ = exp2f(Mx - Mn_); \
    Mx = Mn_; Ls *= al_; \
    _Pragma("unroll") \
    for (int r = 0; r < 16; r++) { O0[r] *= al_; O1[r] *= al_; O2[r] *= al_; O3[r] *= al_; } \
  } \
  _Pragma("unroll") \
  for (int r = 0; r < 16; r++) SS[r] = exp2f(SS[r] - Mx); \
  float ts_[16]; \
  _Pragma("unroll") \
  for (int r = 0; r < 16; r++) ts_[r] = SS[r]; \
  _Pragma("unroll") \
  for (int sft = 8; sft >= 1; sft >>= 1) \
    _Pragma("unroll") \
    for (int r = 0; r < sft; r++) ts_[r] = ts_[r] + ts_[r + sft]; \
  Ls += ts_[0] + __shfl_xor(ts_[0], 32); \
  u32 pk_[8], x_[8]; \
  _Pragma("unroll") \
  for (int m = 0; m < 8; m++) pk_[m] = pack2bf(SS[2 * m], SS[2 * m + 1]); \
  _Pragma("unroll") \
  for (int m = 0; m < 8; m++) x_[m] = __shfl_xor(pk_[m], 32); \
  { \
    u32x4 f0_ = { h8 ? x_[2] : pk_[0], h8 ? x_[3] : pk_[1], \
                  h8 ? pk_[2] : x_[0], h8 ? pk_[3] : x_[1] }; \
    u32x4 f1_ = { h8 ? x_[6] : pk_[4], h8 ? x_[7] : pk_[5], \
                  h8 ? pk_[6] : x_[4], h8 ? pk_[7] : x_[5] }; \
    NPB[0] = __builtin_bit_cast(bf16x8, f0_); \
    NPB[1] = __builtin_bit_cast(bf16x8, f1_); \
  } \
} while (0)

  int vxr = (c32 >> 1) & 3;
  // prologue: stage tile t0, QK^T(t0)
  STAGE_K(t0, 0);
  STAGE_V(t0, 0);
  __syncthreads();
  f32x16 S;
  QKT(S, Ks);
  bf16x8 pA[2];
  // peeled first iteration (no PV yet)
  {
    STAGE_K(t0 + 1, 4096);
    STAGE_V(t0 + 1, 4096);
    SOFTMAX(t0, S, pA);
    __syncthreads();
    QKT(S, Ks + 4096);
  }
  int cur = 1, vb = 1;
  for (int t = t0 + 1; t < t1; t++) {
    bool nxt = (t + 1 < t1);
    if (nxt) {
      STAGE_K(t + 1, (cur ^ 1) * 4096);
      STAGE_V(t + 1, ((vb + 1) % 3) * 4096);
    }
    // PV(t-1) [MFMA] || softmax(t) [VALU] — independent; rescale's O-ops are
    // register-dependent on PV, so ordering is enforced only where needed.
    PVACC(pA, Vs + ((vb + 2) % 3) * 4096);
    bf16x8 pN[2];
    SOFTMAX(t, S, pN);
    pA[0] = pN[0]; pA[1] = pN[1];
    if (nxt) {
      __syncthreads();
      QKT(S, Ks + (cur ^ 1) * 4096);
      cur ^= 1;
      vb = (vb + 1) % 3;
    }
  }
  // tail: PV(t1-1)
  PVACC(pA, Vs + vb * 4096);
#undef STAGE_K
#undef STAGE_V
#undef QKT
#undef PVACC
#undef SOFTMAX
  // epilogue: partial O as bf16 + (Mx, Ls) f32
  {
    u16* Orow = Op + (size_t)sp * 4194304 + (size_t)(qw0 + c32) * 4096 + h * 128;
#pragma unroll
    for (int a = 0; a < 4; a++) {
      u16x4 o0, o1, o2, o3;
#pragma unroll
      for (int b = 0; b < 4; b++) {
        o0[b] = f2bf(O0[4 * a + b]); o1[b] = f2bf(O1[4 * a + b]);
        o2[b] = f2bf(O2[4 * a + b]); o3[b] = f2bf(O3[4 * a + b]);
      }
      int d0 = 8 * a + 4 * h8;
      *(u16x4*)(Orow + d0) = o0;
      *(u16x4*)(Orow + 32 + d0) = o1;
      *(u16x4*)(Orow + 64 + d0) = o2;
      *(u16x4*)(Orow + 96 + d0) = o3;
    }
    if (h8 == 0) {
      float* mp = Ml + ((size_t)(sp * 32 + h) * 1024 + qw0 + c32) * 2;
      mp[0] = Mx; mp[1] = Ls;
    }
  }
}

// ---- combine the four KV-split parts (bf16 partials) -> ctxb bf16 ----
__global__ __launch_bounds__(256) void attn_combine(const u16* __restrict__ Op,
    const float* __restrict__ Ml, u16* __restrict__ ctxb)
{
  int idx = blockIdx.x * 256 + threadIdx.x;  // 1048576
  int q = idx >> 10, c4 = idx & 1023;
  int col = c4 * 4, h = col >> 7;
  float m[4], l[4];
#pragma unroll
  for (int s = 0; s < 4; s++) {
    const float* mp = Ml + ((size_t)(s * 32 + h) * 1024 + q) * 2;
    m[s] = mp[0]; l[s] = mp[1];
  }
  float M = fmaxf(fmaxf(m[0], m[1]), fmaxf(m[2], m[3]));
  float wgt[4];
  float den = 0.f;
#pragma unroll
  for (int s = 0; s < 4; s++) { wgt[s] = exp2f(m[s] - M); den += l[s] * wgt[s]; }
  float inv = 1.0f / den;
  float acc[4] = {0.f, 0.f, 0.f, 0.f};
#pragma unroll
  for (int s = 0; s < 4; s++) {
    u16x4 raw = *(const u16x4*)(Op + (size_t)s * 4194304 + (size_t)q * 4096 + col);
#pragma unroll
    for (int i = 0; i < 4; i++) acc[i] += bf2f(raw[i]) * wgt[s];
  }
  u16x4 o;
#pragma unroll
  for (int i = 0; i < 4; i++) o[i] = f2bf(acc[i] * inv);
  *(u16x4*)(ctxb + (size_t)q * 4096 + col) = o;
}

extern "C" void kernel_launch(void* const* d_in, const int* in_sizes, int n_in,
                              void* d_out, int out_size, void* d_ws, size_t ws_size,
                              hipStream_t stream) {
  const float* x      = (const float*)d_in[0];
  const float* cosb   = (const float*)d_in[2];
  const float* sinb   = (const float*)d_in[3];
  const float* prev_k = (const float*)d_in[5];
  const float* prev_v = (const float*)d_in[6];
  const float* Wq     = (const float*)d_in[7];
  const float* Wk     = (const float*)d_in[8];
  const float* Wv     = (const float*)d_in[9];
  const float* Wo     = (const float*)d_in[10];

  // workspace layout (~144 MB)
  u16* Wt_proj = (u16*)d_ws;                                  // [6144][4096] bf16 (50.3MB)
  u16* Wt_out  = Wt_proj + (size_t)6144 * 4096;               // [4096][4096] bf16
  u16* xb      = Wt_out + (size_t)4096 * 4096;                // [1024][4096] bf16
  float* qkv   = (float*)(xb + (size_t)1024 * 4096);          // [1024][6144] f32 (25.2MB)
  u16* qb      = (u16*)(qkv + (size_t)1024 * 6144);           // [32][1024][128]
  u16* kbb     = qb + (size_t)32 * 1024 * 128;                // [8][4096][128]
  u16* vT      = kbb + (size_t)8 * 4096 * 128;                // [8][128][4096]
  u16* ctxb    = vT + (size_t)8 * 4096 * 128;                 // [1024][4096]
  // attn partials: Op[4] bf16 (33.6MB) aliases Wt_proj (50.3MB, dead after gemm1);
  // Ml aliases qkv (dead after vtrans)
  u16* Op   = (u16*)d_ws;                                     // [4][1024][4096] bf16
  float* Ml = qkv;                                            // [4][32][1024][2] f32

  float* outp   = (float*)d_out;
  float* keys   = outp + (size_t)4194304;
  float* values = outp + (size_t)8388608;

  wtrans<<<4096, 256, 0, stream>>>(Wq, Wt_proj, 4096, 64, 0);
  wtrans<<<1024, 256, 0, stream>>>(Wk, Wt_proj, 1024, 16, 4096);
  wtrans<<<1024, 256, 0, stream>>>(Wv, Wt_proj, 1024, 16, 5120);
  wtrans<<<4096, 256, 0, stream>>>(Wo, Wt_out, 4096, 64, 0);
  cvt_bf16<<<4096, 256, 0, stream>>>(x, xb, 1048576);

  gemm_bt<<<768, 256, 0, stream>>>(xb, Wt_proj, qkv, 6144, 4096, 96);

  rope_q<<<2048, 256, 0, stream>>>(qkv, cosb, sinb, qb);
  rope_k<<<512, 256, 0, stream>>>(qkv, cosb, sinb, keys, kbb);
  copy_vnew<<<1024, 256, 0, stream>>>(qkv, values);
  prev_copy<<<3072, 256, 0, stream>>>(prev_k, prev_v, keys, values, kbb);
  vtrans<<<1024, 256, 0, stream>>>(prev_v, qkv, vT);

  attn_fwd<<<1024, 256, 0, stream>>>(qb, kbb, vT, Op, Ml);
  attn_combine<<<4096, 256, 0, stream>>>(Op, Ml, ctxb);

  gemm_bt<<<512, 256, 0, stream>>>(ctxb, Wt_out, outp, 4096, 4096, 64);
}

// Round 20
// 333.572 us; speedup vs baseline: 1.1942x; 1.0021x over previous
//
#include <hip/hip_runtime.h>
#include <hip/hip_bf16.h>

typedef unsigned short u16;
typedef unsigned int u32;
typedef __attribute__((ext_vector_type(4))) float f32x4;
typedef __attribute__((ext_vector_type(16))) float f32x16;
typedef __attribute__((ext_vector_type(8))) __bf16 bf16x8;
typedef __attribute__((ext_vector_type(4))) u16 u16x4;
typedef __attribute__((ext_vector_type(8))) u16 u16x8;
typedef __attribute__((ext_vector_type(4))) u32 u32x4;

#define START_POS 3072
#define NKV 4096
#define HD_ 128
#define SEQ 1024
#define DIN_ 4096
#define DQKV 6144

__device__ __forceinline__ void gll16(const void* g, void* l) {
  __builtin_amdgcn_global_load_lds((const __attribute__((address_space(1))) u32*)g,
                                   (__attribute__((address_space(3))) u32*)l, 16, 0, 0);
}
__device__ __forceinline__ u16 f2bf(float f) {
  u32 u = __builtin_bit_cast(u32, f);
  return (u16)((u + 0x7fffu + ((u >> 16) & 1u)) >> 16);
}
__device__ __forceinline__ float bf2f(u16 u) {
  u32 x = (u32)u << 16;
  return __builtin_bit_cast(float, x);
}
__device__ __forceinline__ u32 pack2bf(float a, float b) {
  __hip_bfloat162 t = __float22bfloat162_rn(float2{a, b});  // low=a, high=b, RNE
  u32 u; __builtin_memcpy(&u, &t, 4);
  return u;
}
__device__ __forceinline__ f32x4 mfma16(bf16x8 a, bf16x8 b, f32x4 c) {
  return __builtin_amdgcn_mfma_f32_16x16x32_bf16(a, b, c, 0, 0, 0);
}
__device__ __forceinline__ f32x16 mfma32(bf16x8 a, bf16x8 b, f32x16 c) {
  return __builtin_amdgcn_mfma_f32_32x32x16_bf16(a, b, c, 0, 0, 0);
}
__device__ __forceinline__ float max3f(float a, float b, float c) {
  return fmaxf(fmaxf(a, b), c);   // clang fuses to v_max3_f32
}

// ---- transpose+convert W f32 [K=4096][N] -> Wt bf16 [N][4096] ----
__global__ __launch_bounds__(256) void wtrans(const float* __restrict__ W,
    u16* __restrict__ Wt, int N, int ntn, int row_off)
{
  __shared__ float T[64][68];
  int bid = blockIdx.x;
  int nt = bid % ntn, kt = bid / ntn;
  int t = threadIdx.x;
  int kl = t >> 4, nl4 = (t & 15) << 2;
#pragma unroll
  for (int r = 0; r < 4; r++) {
    int row = r * 16 + kl;
    f32x4 v = *(const f32x4*)(W + (size_t)(kt * 64 + row) * N + nt * 64 + nl4);
    T[row][nl4] = v[0]; T[row][nl4 + 1] = v[1]; T[row][nl4 + 2] = v[2]; T[row][nl4 + 3] = v[3];
  }
  __syncthreads();
  int nl = t >> 2, k0 = (t & 3) << 4;
  u16x8 lo, hi;
#pragma unroll
  for (int j = 0; j < 8; j++) lo[j] = f2bf(T[k0 + j][nl]);
#pragma unroll
  for (int j = 0; j < 8; j++) hi[j] = f2bf(T[k0 + 8 + j][nl]);
  u16* dst = Wt + (size_t)(row_off + nt * 64 + nl) * 4096 + kt * 64 + k0;
  *(u16x8*)dst = lo;
  *(u16x8*)(dst + 8) = hi;
}

// ---- f32 -> bf16 convert ----
__global__ __launch_bounds__(256) void cvt_bf16(const float* __restrict__ src,
    u16* __restrict__ dst, int n4)
{
  int i = blockIdx.x * 256 + threadIdx.x;
  if (i >= n4) return;
  f32x4 v = *(const f32x4*)(src + (size_t)i * 4);
  u16x4 o;
#pragma unroll
  for (int j = 0; j < 4; j++) o[j] = f2bf(v[j]);
  *(u16x4*)(dst + (size_t)i * 4) = o;
}

// ---- bf16 GEMM v4: 128x64 tile, BK=64, dbuf 2-phase, T2 swizzle (8-slot rows) ----
__global__ __launch_bounds__(256) void gemm_bt(
    const u16* __restrict__ A, const u16* __restrict__ Bt,
    float* __restrict__ C, int N, int K, int nbx)
{
  __shared__ u16 As[2 * 128 * 64];   // 32KB
  __shared__ u16 Bs[2 * 64 * 64];    // 16KB
  int nwg = (int)gridDim.x;
  int orig = blockIdx.x;
  int q8 = nwg >> 3, r8 = nwg & 7;
  int xcd = orig & 7, jj = orig >> 3;
  int wgid = (xcd < r8 ? xcd * (q8 + 1) : r8 * (q8 + 1) + (xcd - r8) * q8) + jj;
  int by = wgid / nbx, bx = wgid % nbx;
  int tid = threadIdx.x, lane = tid & 63, wid = tid >> 6;
  int wr = wid >> 1, wc = wid & 1;
  int c = lane & 15, hh = lane >> 4;
  int srow = lane >> 3;
  int schunk = ((lane & 7) ^ srow) << 3;
  const u16* aS0 = A + (size_t)(by * 128 + wid * 32 + srow) * K + schunk;
  const u16* bS0 = Bt + (size_t)(bx * 64 + wid * 16 + srow) * K + schunk;

#define GSTAGE(buf, kk) do { \
  _Pragma("unroll") \
  for (int r = 0; r < 4; r++) \
    gll16(aS0 + (size_t)r * 8 * K + (kk), As + (buf) * 8192 + (wid * 32 + r * 8) * 64); \
  _Pragma("unroll") \
  for (int r = 0; r < 2; r++) \
    gll16(bS0 + (size_t)r * 8 * K + (kk), Bs + (buf) * 4096 + (wid * 16 + r * 8) * 64); \
} while (0)

  f32x4 acc[4][2] = {};
  int nk = K >> 6;
  int cur = 0;
  int rsl = c & 7;
  GSTAGE(0, 0);
  __syncthreads();
  for (int kt = 0; kt < nk; kt++) {
    if (kt + 1 < nk) GSTAGE(cur ^ 1, (kt + 1) * 64);
    const u16* Ab = As + cur * 8192;
    const u16* Bb = Bs + cur * 4096;
#pragma unroll
    for (int kk = 0; kk < 2; kk++) {
      int slot = ((kk * 4 + hh) ^ rsl) * 8;
      bf16x8 af[4], bf[2];
#pragma unroll
      for (int i = 0; i < 4; i++)
        af[i] = *(const bf16x8*)(Ab + (wr * 64 + i * 16 + c) * 64 + slot);
#pragma unroll
      for (int i = 0; i < 2; i++)
        bf[i] = *(const bf16x8*)(Bb + (wc * 32 + i * 16 + c) * 64 + slot);
      __builtin_amdgcn_s_setprio(1);
#pragma unroll
      for (int mi = 0; mi < 4; mi++)
#pragma unroll
        for (int ni = 0; ni < 2; ni++)
          acc[mi][ni] = mfma16(af[mi], bf[ni], acc[mi][ni]);
      __builtin_amdgcn_s_setprio(0);
    }
    __syncthreads();
    cur ^= 1;
  }
#undef GSTAGE
  int row0 = by * 128 + wr * 64 + hh * 4;
  int col0 = bx * 64 + wc * 32 + c;
#pragma unroll
  for (int mi = 0; mi < 4; mi++)
#pragma unroll
    for (int ni = 0; ni < 2; ni++)
#pragma unroll
      for (int i = 0; i < 4; i++)
        C[(size_t)(row0 + mi * 16 + i) * N + col0 + ni * 16] = acc[mi][ni][i];
}

// ---- RoPE on q part of qkv -> qb bf16 [32][1024][128], PRE-SCALED by log2(e)/sqrt(128) ----
__global__ __launch_bounds__(256) void rope_q(const float* __restrict__ qkv,
    const float* __restrict__ cosb, const float* __restrict__ sinb, u16* __restrict__ qb)
{
  const float C2 = 0.12751744f;
  int tid = blockIdx.x * 256 + threadIdx.x;  // 524288
  int dq = tid & 15, h = (tid >> 4) & 31, s = tid >> 9;
  int d = dq << 2;
  const float* base = qkv + (size_t)s * DQKV + h * HD_ + d;
  f32x4 a = *(const f32x4*)base;
  f32x4 b2 = *(const f32x4*)(base + 64);
  f32x4 cc = *(const f32x4*)(cosb + (size_t)(START_POS + s) * HD_ + d);
  f32x4 sn = *(const f32x4*)(sinb + (size_t)(START_POS + s) * HD_ + d);
  u16x4 o1, o2;
#pragma unroll
  for (int i = 0; i < 4; i++) {
    o1[i] = f2bf((a[i] * cc[i] - b2[i] * sn[i]) * C2);
    o2[i] = f2bf((b2[i] * cc[i] + a[i] * sn[i]) * C2);
  }
  u16* dst = qb + ((size_t)h * SEQ + s) * HD_ + d;
  *(u16x4*)dst = o1;
  *(u16x4*)(dst + 64) = o2;
}

// ---- RoPE on k part -> keys f32 output (pos>=3072) + kb bf16 ----
__global__ __launch_bounds__(256) void rope_k(const float* __restrict__ qkv,
    const float* __restrict__ cosb, const float* __restrict__ sinb,
    float* __restrict__ keys, u16* __restrict__ kbb)
{
  int tid = blockIdx.x * 256 + threadIdx.x;  // 131072
  int dq = tid & 15, g = (tid >> 4) & 7, s = tid >> 7;
  int d = dq << 2;
  const float* base = qkv + (size_t)s * DQKV + DIN_ + g * HD_ + d;
  f32x4 a = *(const f32x4*)base;
  f32x4 b2 = *(const f32x4*)(base + 64);
  f32x4 cc = *(const f32x4*)(cosb + (size_t)(START_POS + s) * HD_ + d);
  f32x4 sn = *(const f32x4*)(sinb + (size_t)(START_POS + s) * HD_ + d);
  f32x4 o1, o2;
  u16x4 p1, p2;
#pragma unroll
  for (int i = 0; i < 4; i++) {
    o1[i] = a[i] * cc[i] - b2[i] * sn[i];
    o2[i] = b2[i] * cc[i] + a[i] * sn[i];
    p1[i] = f2bf(o1[i]);
    p2[i] = f2bf(o2[i]);
  }
  size_t off = ((size_t)g * NKV + START_POS + s) * HD_ + d;
  *(f32x4*)(keys + off) = o1;
  *(f32x4*)(keys + off + 64) = o2;
  *(u16x4*)(kbb + off) = p1;
  *(u16x4*)(kbb + off + 64) = p2;
}

// ---- copy v part -> values f32 output (pos>=3072) ----
__global__ __launch_bounds__(256) void copy_vnew(const float* __restrict__ qkv,
    float* __restrict__ values)
{
  int tid = blockIdx.x * 256 + threadIdx.x;  // 262144
  int dq = tid & 31, g = (tid >> 5) & 7, s = tid >> 8;
  int d = dq << 2;
  f32x4 v = *(const f32x4*)(qkv + (size_t)s * DQKV + DIN_ + 1024 + g * HD_ + d);
  *(f32x4*)(values + ((size_t)g * NKV + START_POS + s) * HD_ + d) = v;
}

// ---- copy prev_k/prev_v -> keys/values f32 outputs + kb bf16 ----
__global__ __launch_bounds__(256) void prev_copy(const float* __restrict__ pk,
    const float* __restrict__ pv, float* __restrict__ keys, float* __restrict__ values,
    u16* __restrict__ kbb)
{
  int idx = blockIdx.x * 256 + threadIdx.x;  // 786432 quads
  int d4 = idx & 31;
  int rest = idx >> 5;
  int p = rest % 3072, g = rest / 3072;
  f32x4 kq = *(const f32x4*)(pk + (size_t)idx * 4);
  f32x4 vq = *(const f32x4*)(pv + (size_t)idx * 4);
  size_t off = ((size_t)g * NKV + p) * HD_ + d4 * 4;
  *(f32x4*)(keys + off) = kq;
  *(f32x4*)(values + off) = vq;
  u16x4 kb4;
#pragma unroll
  for (int i = 0; i < 4; i++) kb4[i] = f2bf(kq[i]);
  *(u16x4*)(kbb + off) = kb4;
}

// ---- build vT bf16 [8][128][4096] from prev_v (pos<3072) / qkv v-cols ----
__global__ __launch_bounds__(256) void vtrans(const float* __restrict__ pv,
    const float* __restrict__ qkv, u16* __restrict__ vT)
{
  __shared__ float T[64][68];
  int bid = blockIdx.x;  // 1024 = g(8) * pt(64) * dt(2)
  int dt = bid & 1, pt = (bid >> 1) & 63, g = bid >> 7;
  int t = threadIdx.x;
  int pl = t >> 4, dl4 = (t & 15) << 2;
#pragma unroll
  for (int r = 0; r < 4; r++) {
    int row = r * 16 + pl;
    int pos = pt * 64 + row;
    f32x4 v;
    if (pos < START_POS)
      v = *(const f32x4*)(pv + ((size_t)g * START_POS + pos) * HD_ + dt * 64 + dl4);
    else
      v = *(const f32x4*)(qkv + (size_t)(pos - START_POS) * DQKV + 5120 + g * HD_ + dt * 64 + dl4);
    T[row][dl4] = v[0]; T[row][dl4 + 1] = v[1]; T[row][dl4 + 2] = v[2]; T[row][dl4 + 3] = v[3];
  }
  __syncthreads();
  int dl = t >> 2, p0 = (t & 3) << 4;
  u16x8 lo, hi;
#pragma unroll
  for (int j = 0; j < 8; j++) lo[j] = f2bf(T[p0 + j][dl]);
#pragma unroll
  for (int j = 0; j < 8; j++) hi[j] = f2bf(T[p0 + 8 + j][dl]);
  u16* dst = vT + ((size_t)g * HD_ + dt * 64 + dl) * NKV + pt * 64 + p0;
  *(u16x8*)dst = lo;
  *(u16x8*)(dst + 8) = hi;
}

// ---- flash attention v10: v9 (T15 pipeline) + counted vmcnt barriers (T4):
// ---- mid-loop waits vmcnt(2) (K done, V in flight), raw s_barrier. max3 tree. ----
__global__ __launch_bounds__(256, 2) void attn_fwd(
    const u16* __restrict__ qb, const u16* __restrict__ kb,
    const u16* __restrict__ vT, u16* __restrict__ Op, float* __restrict__ Ml)
{
  __shared__ u16 Ks[2 * 32 * 128];   // [buf][kv 32][d 128], 16B-slot XOR swizzle
  __shared__ u16 Vs[3 * 128 * 32];   // [buf][d 128][kv 32], slot^((d>>1)&3) swizzle
  int bid = blockIdx.x;
  int g = bid & 7, j = bid >> 3;     // XCD x owns KV group g=x; j in [0,128)
  int sp = j >> 5, jj = j & 31;      // sp in {0,1,2,3}
  int h = g * 4 + (jj >> 3), qt = jj & 7;
  int tid = threadIdx.x, lane = tid & 63, w = tid >> 6;   // w in [0,4)
  int c32 = lane & 31, h8 = lane >> 5;
  int qw0 = qt * 128 + w * 32;       // this wave's first q row
  bf16x8 Qf[8];
#pragma unroll
  for (int dc = 0; dc < 8; dc++)
    Qf[dc] = *(const bf16x8*)(qb + ((size_t)(h * 1024 + qw0 + c32)) * 128 + dc * 16 + h8 * 8);
  f32x16 O0 = {}, O1 = {}, O2 = {}, O3 = {};
  float Mx = -1e30f, Ls = 0.f;
  int T = 100 + 4 * qt;
  int t0 = (sp * T) >> 2;
  int t1 = ((sp + 1) * T) >> 2;      // t1-t0 >= 25; first tile of each sp unmasked

// K staged BEFORE V each tile -> vmcnt(2) drains K (oldest-first), leaves V in flight
#define STAGE_K(tt, bo) do { \
  _Pragma("unroll") \
  for (int r = 0; r < 2; r++) { \
    int s = r * 256 + w * 64 + lane; \
    int krow = s >> 4, sl = s & 15; \
    gll16(kb + ((size_t)(g * 4096 + (tt) * 32 + krow)) * 128 + (sl ^ (krow & 7)) * 8, \
          Ks + (bo) + (r * 256 + w * 64) * 8); \
  } \
} while (0)
#define STAGE_V(tt, bo) do { \
  _Pragma("unroll") \
  for (int r = 0; r < 2; r++) { \
    int s = r * 256 + w * 64 + lane; \
    int d = s >> 2, sl2 = s & 3; \
    gll16(vT + ((size_t)(g * 128 + d)) * 4096 + (tt) * 32 + (sl2 ^ ((d >> 1) & 3)) * 8, \
          Vs + (bo) + (r * 256 + w * 64) * 8); \
  } \
} while (0)

#define KBAR() do { \
  asm volatile("s_waitcnt vmcnt(2)" ::: "memory"); \
  __builtin_amdgcn_sched_barrier(0); \
  __builtin_amdgcn_s_barrier(); \
  __builtin_amdgcn_sched_barrier(0); \
} while (0)

#define QKT(SS, kbase) do { \
  f32x16 s0_ = {}, sb_ = {}; \
  __builtin_amdgcn_s_setprio(1); \
  _Pragma("unroll") \
  for (int dc = 0; dc < 8; dc += 2) { \
    int sxA_ = (2 * dc + h8) ^ (c32 & 7); \
    int sxB_ = (2 * dc + 2 + h8) ^ (c32 & 7); \
    bf16x8 kA_ = *(const bf16x8*)((kbase) + (size_t)c32 * 128 + sxA_ * 8); \
    bf16x8 kB_ = *(const bf16x8*)((kbase) + (size_t)c32 * 128 + sxB_ * 8); \
    s0_ = mfma32(kA_, Qf[dc], s0_); \
    sb_ = mfma32(kB_, Qf[dc + 1], sb_); \
  } \
  __builtin_amdgcn_s_setprio(0); \
  _Pragma("unroll") \
  for (int r = 0; r < 16; r++) SS[r] = s0_[r] + sb_[r]; \
} while (0)

#define PVACC(PB, vbase) do { \
  __builtin_amdgcn_s_setprio(1); \
  _Pragma("unroll") \
  for (int kc = 0; kc < 2; kc++) { \
    int sx_ = ((2 * kc + h8) ^ vxr) * 8; \
    O0 = mfma32(*(const bf16x8*)((vbase) + (size_t)(0 * 32 + c32) * 32 + sx_), PB[kc], O0); \
    O1 = mfma32(*(const bf16x8*)((vbase) + (size_t)(1 * 32 + c32) * 32 + sx_), PB[kc], O1); \
    O2 = mfma32(*(const bf16x8*)((vbase) + (size_t)(2 * 32 + c32) * 32 + sx_), PB[kc], O2); \
    O3 = mfma32(*(const bf16x8*)((vbase) + (size_t)(3 * 32 + c32) * 32 + sx_), PB[kc], O3); \
  } \
  __builtin_amdgcn_s_setprio(0); \
} while (0)

#define SOFTMAX(tt, SS, NPB) do { \
  if ((tt) * 32 + 31 > START_POS + qw0) { \
    int qa_ = START_POS + qw0 + c32; \
    _Pragma("unroll") \
    for (int r = 0; r < 16; r++) { \
      int kvo_ = (tt) * 32 + (r & 3) + 8 * (r >> 2) + 4 * h8; \
      if (kvo_ > qa_) SS[r] = -1e30f; \
    } \
  } \
  float a1_ = max3f(SS[0], SS[1], SS[2]); \
  float a2_ = max3f(SS[3], SS[4], SS[5]); \
  float a3_ = max3f(SS[6], SS[7], SS[8]); \
  float a4_ = max3f(SS[9], SS[10], SS[11]); \
  float a5_ = max3f(SS[12], SS[13], SS[14]); \
  float b1_ = max3f(a1_, a2_, a3_); \
  float b2_ = max3f(a4_, a5_, SS[15]); \
  float mt_ = fmaxf(b1_, b2_); \
  float full_ = fmaxf(mt_, __shfl_xor(mt_, 32)); \
  if (!__all(full_ <= Mx + 8.0f)) { \
    float Mn_ = fmaxf(Mx, full_); \
    float al_ = exp2f(Mx - Mn_); \
    Mx = Mn_; Ls *= al_; \
    _Pragma("unroll") \
    for (int r = 0; r < 16; r++) { O0[r] *= al_; O1[r] *= al_; O2[r] *= al_; O3[r] *= al_; } \
  } \
  _Pragma("unroll") \
  for (int r = 0; r < 16; r++) SS[r] = exp2f(SS[r] - Mx); \
  float ts_[16]; \
  _Pragma("unroll") \
  for (int r = 0; r < 16; r++) ts_[r] = SS[r]; \
  _Pragma("unroll") \
  for (int sft = 8; sft >= 1; sft >>= 1) \
    _Pragma("unroll") \
    for (int r = 0; r < sft; r++) ts_[r] = ts_[r] + ts_[r + sft]; \
  Ls += ts_[0] + __shfl_xor(ts_[0], 32); \
  u32 pk_[8], x_[8]; \
  _Pragma("unroll") \
  for (int m = 0; m < 8; m++) pk_[m] = pack2bf(SS[2 * m], SS[2 * m + 1]); \
  _Pragma("unroll") \
  for (int m = 0; m < 8; m++) x_[m] = __shfl_xor(pk_[m], 32); \
  { \
    u32x4 f0_ = { h8 ? x_[2] : pk_[0], h8 ? x_[3] : pk_[1], \
                  h8 ? pk_[2] : x_[0], h8 ? pk_[3] : x_[1] }; \
    u32x4 f1_ = { h8 ? x_[6] : pk_[4], h8 ? x_[7] : pk_[5], \
                  h8 ? pk_[6] : x_[4], h8 ? pk_[7] : x_[5] }; \
    NPB[0] = __builtin_bit_cast(bf16x8, f0_); \
    NPB[1] = __builtin_bit_cast(bf16x8, f1_); \
  } \
} while (0)

  int vxr = (c32 >> 1) & 3;
  // prologue: stage tile t0 (K then V), full drain, QK^T(t0)
  STAGE_K(t0, 0);
  STAGE_V(t0, 0);
  __syncthreads();
  f32x16 S;
  QKT(S, Ks);
  bf16x8 pA[2];
  // peeled first iteration (no PV yet); V(t0+1) stays in flight across KBAR
  {
    STAGE_K(t0 + 1, 4096);
    STAGE_V(t0 + 1, 4096);
    SOFTMAX(t0, S, pA);
    KBAR();
    QKT(S, Ks + 4096);
  }
  int cur = 1, vb = 1;
  for (int t = t0 + 1; t < t1; t++) {
    bool nxt = (t + 1 < t1);
    if (nxt) {
      STAGE_K(t + 1, (cur ^ 1) * 4096);
      STAGE_V(t + 1, ((vb + 1) % 3) * 4096);
    }
    // PV(t-1) [MFMA] || softmax(t) [VALU]
    PVACC(pA, Vs + ((vb + 2) % 3) * 4096);
    bf16x8 pN[2];
    SOFTMAX(t, S, pN);
    pA[0] = pN[0]; pA[1] = pN[1];
    if (nxt) {
      KBAR();                         // K(t+1) resident; V(t+1) still in flight
      QKT(S, Ks + (cur ^ 1) * 4096);
      cur ^= 1;
      vb = (vb + 1) % 3;
    }
  }
  // tail: drain the last V before final PV
  asm volatile("s_waitcnt vmcnt(0)" ::: "memory");
  __builtin_amdgcn_sched_barrier(0);
  __builtin_amdgcn_s_barrier();
  __builtin_amdgcn_sched_barrier(0);
  PVACC(pA, Vs + vb * 4096);
#undef STAGE_K
#undef STAGE_V
#undef KBAR
#undef QKT
#undef PVACC
#undef SOFTMAX
  // epilogue: partial O as bf16 + (Mx, Ls) f32
  {
    u16* Orow = Op + (size_t)sp * 4194304 + (size_t)(qw0 + c32) * 4096 + h * 128;
#pragma unroll
    for (int a = 0; a < 4; a++) {
      u16x4 o0, o1, o2, o3;
#pragma unroll
      for (int b = 0; b < 4; b++) {
        o0[b] = f2bf(O0[4 * a + b]); o1[b] = f2bf(O1[4 * a + b]);
        o2[b] = f2bf(O2[4 * a + b]); o3[b] = f2bf(O3[4 * a + b]);
      }
      int d0 = 8 * a + 4 * h8;
      *(u16x4*)(Orow + d0) = o0;
      *(u16x4*)(Orow + 32 + d0) = o1;
      *(u16x4*)(Orow + 64 + d0) = o2;
      *(u16x4*)(Orow + 96 + d0) = o3;
    }
    if (h8 == 0) {
      float* mp = Ml + ((size_t)(sp * 32 + h) * 1024 + qw0 + c32) * 2;
      mp[0] = Mx; mp[1] = Ls;
    }
  }
}

// ---- combine the four KV-split parts (bf16 partials) -> ctxb bf16 ----
__global__ __launch_bounds__(256) void attn_combine(const u16* __restrict__ Op,
    const float* __restrict__ Ml, u16* __restrict__ ctxb)
{
  int idx = blockIdx.x * 256 + threadIdx.x;  // 1048576
  int q = idx >> 10, c4 = idx & 1023;
  int col = c4 * 4, h = col >> 7;
  float m[4], l[4];
#pragma unroll
  for (int s = 0; s < 4; s++) {
    const float* mp = Ml + ((size_t)(s * 32 + h) * 1024 + q) * 2;
    m[s] = mp[0]; l[s] = mp[1];
  }
  float M = fmaxf(fmaxf(m[0], m[1]), fmaxf(m[2], m[3]));
  float wgt[4];
  float den = 0.f;
#pragma unroll
  for (int s = 0; s < 4; s++) { wgt[s] = exp2f(m[s] - M); den += l[s] * wgt[s]; }
  float inv = 1.0f / den;
  float acc[4] = {0.f, 0.f, 0.f, 0.f};
#pragma unroll
  for (int s = 0; s < 4; s++) {
    u16x4 raw = *(const u16x4*)(Op + (size_t)s * 4194304 + (size_t)q * 4096 + col);
#pragma unroll
    for (int i = 0; i < 4; i++) acc[i] += bf2f(raw[i]) * wgt[s];
  }
  u16x4 o;
#pragma unroll
  for (int i = 0; i < 4; i++) o[i] = f2bf(acc[i] * inv);
  *(u16x4*)(ctxb + (size_t)q * 4096 + col) = o;
}

extern "C" void kernel_launch(void* const* d_in, const int* in_sizes, int n_in,
                              void* d_out, int out_size, void* d_ws, size_t ws_size,
                              hipStream_t stream) {
  const float* x      = (const float*)d_in[0];
  const float* cosb   = (const float*)d_in[2];
  const float* sinb   = (const float*)d_in[3];
  const float* prev_k = (const float*)d_in[5];
  const float* prev_v = (const float*)d_in[6];
  const float* Wq     = (const float*)d_in[7];
  const float* Wk     = (const float*)d_in[8];
  const float* Wv     = (const float*)d_in[9];
  const float* Wo     = (const float*)d_in[10];

  // workspace layout (~144 MB)
  u16* Wt_proj = (u16*)d_ws;                                  // [6144][4096] bf16 (50.3MB)
  u16* Wt_out  = Wt_proj + (size_t)6144 * 4096;               // [4096][4096] bf16
  u16* xb      = Wt_out + (size_t)4096 * 4096;                // [1024][4096] bf16
  float* qkv   = (float*)(xb + (size_t)1024 * 4096);          // [1024][6144] f32 (25.2MB)
  u16* qb      = (u16*)(qkv + (size_t)1024 * 6144);           // [32][1024][128]
  u16* kbb     = qb + (size_t)32 * 1024 * 128;                // [8][4096][128]
  u16* vT      = kbb + (size_t)8 * 4096 * 128;                // [8][128][4096]
  u16* ctxb    = vT + (size_t)8 * 4096 * 128;                 // [1024][4096]
  // attn partials: Op[4] bf16 (33.6MB) aliases Wt_proj (50.3MB, dead after gemm1);
  // Ml aliases qkv (dead after vtrans)
  u16* Op   = (u16*)d_ws;                                     // [4][1024][4096] bf16
  float* Ml = qkv;                                            // [4][32][1024][2] f32

  float* outp   = (float*)d_out;
  float* keys   = outp + (size_t)4194304;
  float* values = outp + (size_t)8388608;

  wtrans<<<4096, 256, 0, stream>>>(Wq, Wt_proj, 4096, 64, 0);
  wtrans<<<1024, 256, 0, stream>>>(Wk, Wt_proj, 1024, 16, 4096);
  wtrans<<<1024, 256, 0, stream>>>(Wv, Wt_proj, 1024, 16, 5120);
  wtrans<<<4096, 256, 0, stream>>>(Wo, Wt_out, 4096, 64, 0);
  cvt_bf16<<<4096, 256, 0, stream>>>(x, xb, 1048576);

  gemm_bt<<<768, 256, 0, stream>>>(xb, Wt_proj, qkv, 6144, 4096, 96);

  rope_q<<<2048, 256, 0, stream>>>(qkv, cosb, sinb, qb);
  rope_k<<<512, 256, 0, stream>>>(qkv, cosb, sinb, keys, kbb);
  copy_vnew<<<1024, 256, 0, stream>>>(qkv, values);
  prev_copy<<<3072, 256, 0, stream>>>(prev_k, prev_v, keys, values, kbb);
  vtrans<<<1024, 256, 0, stream>>>(prev_v, qkv, vT);

  attn_fwd<<<1024, 256, 0, stream>>>(qb, kbb, vT, Op, Ml);
  attn_combine<<<4096, 256, 0, stream>>>(Op, Ml, ctxb);

  gemm_bt<<<512, 256, 0, stream>>>(ctxb, Wt_out, outp, 4096, 4096, 64);
}